// Round 9
// baseline (362.153 us; speedup 1.0000x reference)
//
#include <hip/hip_runtime.h>
#include <hip/hip_bf16.h>

typedef __hip_bfloat16 bf16;
typedef __attribute__((ext_vector_type(8))) short short8;
typedef __attribute__((ext_vector_type(4))) float f32x4;

#define AS1 __attribute__((address_space(1)))
#define AS3 __attribute__((address_space(3)))

__device__ __forceinline__ void gload_lds16(const bf16* gp, bf16* lp) {
  __builtin_amdgcn_global_load_lds((const AS1 void*)gp, (AS3 void*)lp, 16, 0, 0);
}

__device__ __forceinline__ float fast_exp2(float x) {
#if __has_builtin(__builtin_amdgcn_exp2f)
  return __builtin_amdgcn_exp2f(x);
#else
  return exp2f(x);
#endif
}

__device__ __forceinline__ void store_c(bf16* C, size_t idx, float v) { C[idx] = __float2bfloat16(v); }
__device__ __forceinline__ void store_c(float* C, size_t idx, float v) { C[idx] = v; }

struct __align__(8) b16x4 { bf16 a, b, c, d; };

// ---------------------------------------------------------------------------
// prep_all: ONE kernel for (a) fp32->bf16 convert of x, (b) RoPE cos/sin
// table, (c) all 8 weight transposes. Block-ranged dispatch:
// [0,8192) cvt | [8192,8448) tab | [8448, 8448+cum) prep.
// r5 lesson preserved: trig calls live ONLY in the tab range (nothing live
// across them).
// ---------------------------------------------------------------------------
struct PrepArgs {
  const float* src[8];
  bf16* dst[8];
  int R[8], C[8], cum[8];
};

__global__ void prep_all(const float* __restrict__ x, bf16* __restrict__ xbf,
                         float2* __restrict__ ctab, PrepArgs a)
{
  const int blk = blockIdx.x;
  const int tid = threadIdx.x;
  if (blk < 8192) {                       // ---- cvt x -> xbf ----
    const int i = (blk * 256 + tid) * 4;
    const float4 v = *(const float4*)(x + i);
    xbf[i + 0] = __float2bfloat16(v.x);
    xbf[i + 1] = __float2bfloat16(v.y);
    xbf[i + 2] = __float2bfloat16(v.z);
    xbf[i + 3] = __float2bfloat16(v.w);
    return;
  }
  if (blk < 8448) {                       // ---- RoPE table ----
    const int idx = (blk - 8192) * 256 + tid;   // 65536 entries
    const int i = idx & 31;
    const int s = idx >> 5;
    const float inv = fast_exp2(-(float)i * 0.41524101186092029f);
    const float ang = (float)s * inv;
    ctab[idx] = make_float2(cosf(ang), sinf(ang));
    return;
  }
  // ---- weight transposes (fp32 [R][C] -> bf16 [C][R]) ----
  __shared__ bf16 t[32][33];
  const int pb = blk - 8448;
  int e = 0;
  while (e < 7 && pb >= a.cum[e]) ++e;
  const int lt = pb - (e ? a.cum[e - 1] : 0);
  const int R = a.R[e], C = a.C[e];
  const int tpr = C >> 5;
  const int bx = lt % tpr, by = lt / tpr;
  const float* in = a.src[e];
  bf16* out = a.dst[e];
  const int c0 = bx * 32, r0 = by * 32;
  const int tx = tid & 31, ty = tid >> 5;
  for (int i = 0; i < 4; ++i)
    t[ty + 8 * i][tx] = __float2bfloat16(in[(size_t)(r0 + ty + 8 * i) * C + c0 + tx]);
  __syncthreads();
  for (int i = 0; i < 4; ++i)
    out[(size_t)(c0 + ty + 8 * i) * R + r0 + tx] = t[tx][ty + 8 * i];
}

// ---------------------------------------------------------------------------
// Generic bf16 GEMM, C = A @ B with B supplied transposed (Bt[N][K]).
// r6: T3-minimum double-buffered staging (counted vmcnt(4), raw s_barrier).
// r9: MODE 0 is SPLIT-K (gridDim.z = 2): each z-half accumulates K/2 and
// atomicAdds f32 into C (caller memsets C). 1024 blocks = 3-4/CU vs 512 =
// 2/CU — the m97 structure's latency-exposed regime (m102: N=2048 -> 320 TF
// at 2/CU vs 912 at 4/CU). gemm1 (MODE 4) can't split safely (bf16+rope
// epilogue would need a colliding f32 temp) — unchanged.
// ---------------------------------------------------------------------------
template <typename CT, int MODE>
__global__ void gemm_bt(const bf16* __restrict__ A, int lda,
                        const bf16* __restrict__ Bt,
                        CT* __restrict__ C, bf16* __restrict__ C2, int ldc,
                        int K, const float2* __restrict__ ctab)
{
  __shared__ __align__(16) bf16 As[2][128 * 32];
  __shared__ __align__(16) bf16 Bs[2][128 * 32];
  const int tid  = threadIdx.x;
  const int wave = tid >> 6, lane = tid & 63;
  const int quad = lane >> 4, l16 = lane & 15;
  const int m0 = blockIdx.y * 128, n0 = blockIdx.x * 128;
  const int wm = (wave >> 1) * 64, wn = (wave & 1) * 64;

  const int kspan = (MODE == 0) ? (K >> 1) : K;
  const int kbase = (MODE == 0) ? (int)blockIdx.z * kspan : 0;
  const int kend  = kbase + kspan;

  f32x4 acc[4][4];
#pragma unroll
  for (int i = 0; i < 4; ++i)
#pragma unroll
    for (int j = 0; j < 4; ++j) acc[i][j] = (f32x4){0.f, 0.f, 0.f, 0.f};

  const int r1  = tid >> 2;
  const int ks1 = (tid & 3) * 8;

  gload_lds16(A  + (size_t)(m0 + r1)      * lda + kbase + ks1, &As[0][tid * 8]);
  gload_lds16(A  + (size_t)(m0 + r1 + 64) * lda + kbase + ks1, &As[0][(tid + 256) * 8]);
  gload_lds16(Bt + (size_t)(n0 + r1)      * K   + kbase + ks1, &Bs[0][tid * 8]);
  gload_lds16(Bt + (size_t)(n0 + r1 + 64) * K   + kbase + ks1, &Bs[0][(tid + 256) * 8]);

  int cur = 0;
  for (int k0 = kbase; k0 < kend; k0 += 32) {
    if (k0 + 32 < kend) {               // prefetch next tile into buf^1
      const int kn = k0 + 32;
      const int nxt = cur ^ 1;
      gload_lds16(A  + (size_t)(m0 + r1)      * lda + kn + ks1, &As[nxt][tid * 8]);
      gload_lds16(A  + (size_t)(m0 + r1 + 64) * lda + kn + ks1, &As[nxt][(tid + 256) * 8]);
      gload_lds16(Bt + (size_t)(n0 + r1)      * K   + kn + ks1, &Bs[nxt][tid * 8]);
      gload_lds16(Bt + (size_t)(n0 + r1 + 64) * K   + kn + ks1, &Bs[nxt][(tid + 256) * 8]);
      asm volatile("s_waitcnt vmcnt(4)" ::: "memory");
    } else {
      asm volatile("s_waitcnt vmcnt(0)" ::: "memory");
    }
    __builtin_amdgcn_s_barrier();

    short8 af[4], bf_[4];
#pragma unroll
    for (int mt = 0; mt < 4; ++mt)
      af[mt] = *(const short8*)&As[cur][(wm + mt * 16 + l16) * 32 + quad * 8];
#pragma unroll
    for (int nt = 0; nt < 4; ++nt)
      bf_[nt] = *(const short8*)&Bs[cur][(wn + nt * 16 + l16) * 32 + quad * 8];
#pragma unroll
    for (int mt = 0; mt < 4; ++mt)
#pragma unroll
      for (int nt = 0; nt < 4; ++nt)
        acc[mt][nt] = __builtin_amdgcn_mfma_f32_16x16x32_bf16(af[mt], bf_[nt], acc[mt][nt], 0, 0, 0);
    __builtin_amdgcn_s_barrier();
    cur ^= 1;
  }

  if (MODE == 0) {
    // split-K: accumulate into pre-zeroed f32 C
#pragma unroll
    for (int mt = 0; mt < 4; ++mt) {
      const int row = m0 + wm + mt * 16 + quad * 4;
#pragma unroll
      for (int nt = 0; nt < 4; ++nt) {
        const int cn = n0 + wn + nt * 16 + l16;
        const f32x4 v = acc[mt][nt];
#pragma unroll
        for (int r = 0; r < 4; ++r)
          atomicAdd((float*)&C[(size_t)(row + r) * ldc + cn], v[r]);
      }
    }
  } else if (MODE == 4) {
    if (n0 < 1024) {
#pragma unroll
      for (int mt = 0; mt < 4; ++mt) {
        const int row = m0 + wm + mt * 16 + quad * 4;
#pragma unroll
        for (int nt = 0; nt < 4; ++nt) {
          const int cn = n0 + wn + nt * 16 + l16;
          const f32x4 v = acc[mt][nt];
#pragma unroll
          for (int r = 0; r < 4; ++r)
            store_c(C, (size_t)(row + r) * 1024 + cn, v[r]);
        }
      }
    } else {
      // k_rope path: RoPE via table lookup (no trig calls -> no spills)
#pragma unroll
      for (int mt = 0; mt < 4; ++mt) {
        const int row = m0 + wm + mt * 16 + quad * 4;
        f32x4 w[4];
#pragma unroll
        for (int nt = 0; nt < 4; ++nt) w[nt] = acc[mt][nt];
#pragma unroll
        for (int r = 0; r < 4; ++r) {
          const int s = (row + r) & 2047;
          const float2 cs0 = ctab[(s << 5) + l16];
          const float2 cs1 = ctab[(s << 5) + 16 + l16];
          const float x1a = w[0][r], x2a = w[2][r];
          const float x1b = w[1][r], x2b = w[3][r];
          w[0][r] = x1a * cs0.x - x2a * cs0.y;
          w[2][r] = x2a * cs0.x + x1a * cs0.y;
          w[1][r] = x1b * cs1.x - x2b * cs1.y;
          w[3][r] = x2b * cs1.x + x1b * cs1.y;
        }
#pragma unroll
        for (int nt = 0; nt < 4; ++nt) {
          const int cn2 = n0 + wn + nt * 16 + l16 - 1024;
          const int g = ((cn2 >> 6) << 7) + 64 + (cn2 & 63);
#pragma unroll
          for (int r = 0; r < 4; ++r)
            C2[(size_t)(row + r) * 2048 + g] = __float2bfloat16(w[nt][r]);
        }
      }
    }
  }
}

// ---------------------------------------------------------------------------
// Fused up-projection GEMM: k_nope+vT (N=3072) and q-interleave (N=2048).
// K=512, lda=1024. grid=(40,32) = 1280 blocks = 5/CU (no split needed).
// ---------------------------------------------------------------------------
__global__ void gemm_up_fused(const bf16* __restrict__ latcat,
                              const bf16* __restrict__ wtUP,
                              const bf16* __restrict__ wtQcat,
                              bf16* __restrict__ vT, bf16* __restrict__ kfull,
                              bf16* __restrict__ qfull,
                              const float2* __restrict__ ctab)
{
  const bool is2 = (blockIdx.x >= 24);
  const bf16* A  = latcat + (is2 ? 512 : 0);
  const bf16* Bt = is2 ? wtQcat : wtUP;
  const int n0 = (is2 ? (int)blockIdx.x - 24 : (int)blockIdx.x) * 128;
  const int K = 512, lda = 1024;

  __shared__ __align__(16) bf16 As[2][128 * 32];
  __shared__ __align__(16) bf16 Bs[2][128 * 32];
  const int tid  = threadIdx.x;
  const int wave = tid >> 6, lane = tid & 63;
  const int quad = lane >> 4, l16 = lane & 15;
  const int m0 = blockIdx.y * 128;
  const int wm = (wave >> 1) * 64, wn = (wave & 1) * 64;

  f32x4 acc[4][4];
#pragma unroll
  for (int i = 0; i < 4; ++i)
#pragma unroll
    for (int j = 0; j < 4; ++j) acc[i][j] = (f32x4){0.f, 0.f, 0.f, 0.f};

  const int r1  = tid >> 2;
  const int ks1 = (tid & 3) * 8;

  gload_lds16(A  + (size_t)(m0 + r1)      * lda + ks1, &As[0][tid * 8]);
  gload_lds16(A  + (size_t)(m0 + r1 + 64) * lda + ks1, &As[0][(tid + 256) * 8]);
  gload_lds16(Bt + (size_t)(n0 + r1)      * K   + ks1, &Bs[0][tid * 8]);
  gload_lds16(Bt + (size_t)(n0 + r1 + 64) * K   + ks1, &Bs[0][(tid + 256) * 8]);

  int cur = 0;
  for (int k0 = 0; k0 < K; k0 += 32) {
    if (k0 + 32 < K) {
      const int kn = k0 + 32;
      const int nxt = cur ^ 1;
      gload_lds16(A  + (size_t)(m0 + r1)      * lda + kn + ks1, &As[nxt][tid * 8]);
      gload_lds16(A  + (size_t)(m0 + r1 + 64) * lda + kn + ks1, &As[nxt][(tid + 256) * 8]);
      gload_lds16(Bt + (size_t)(n0 + r1)      * K   + kn + ks1, &Bs[nxt][tid * 8]);
      gload_lds16(Bt + (size_t)(n0 + r1 + 64) * K   + kn + ks1, &Bs[nxt][(tid + 256) * 8]);
      asm volatile("s_waitcnt vmcnt(4)" ::: "memory");
    } else {
      asm volatile("s_waitcnt vmcnt(0)" ::: "memory");
    }
    __builtin_amdgcn_s_barrier();

    short8 af[4], bf_[4];
#pragma unroll
    for (int mt = 0; mt < 4; ++mt)
      af[mt] = *(const short8*)&As[cur][(wm + mt * 16 + l16) * 32 + quad * 8];
#pragma unroll
    for (int nt = 0; nt < 4; ++nt)
      bf_[nt] = *(const short8*)&Bs[cur][(wn + nt * 16 + l16) * 32 + quad * 8];
#pragma unroll
    for (int mt = 0; mt < 4; ++mt)
#pragma unroll
      for (int nt = 0; nt < 4; ++nt)
        acc[mt][nt] = __builtin_amdgcn_mfma_f32_16x16x32_bf16(af[mt], bf_[nt], acc[mt][nt], 0, 0, 0);
    __builtin_amdgcn_s_barrier();
    cur ^= 1;
  }

  if (is2) {
    if (n0 < 1024) {
#pragma unroll
      for (int mt = 0; mt < 4; ++mt) {
        const int row = m0 + wm + mt * 16 + quad * 4;
#pragma unroll
        for (int nt = 0; nt < 4; ++nt) {
          const int cn = n0 + wn + nt * 16 + l16;
          const int g = (((cn >> 6) & 15) << 7) + ((cn >> 10) << 6) + (cn & 63);
          const f32x4 v = acc[mt][nt];
#pragma unroll
          for (int r = 0; r < 4; ++r)
            qfull[(size_t)(row + r) * 2048 + g] = __float2bfloat16(v[r]);
        }
      }
    } else {
      // q_rope half: RoPE via table lookup, then interleave store
#pragma unroll
      for (int mt = 0; mt < 4; ++mt) {
        const int row = m0 + wm + mt * 16 + quad * 4;
        f32x4 w[4];
#pragma unroll
        for (int nt = 0; nt < 4; ++nt) w[nt] = acc[mt][nt];
#pragma unroll
        for (int r = 0; r < 4; ++r) {
          const int s = (row + r) & 2047;
          const float2 cs0 = ctab[(s << 5) + l16];
          const float2 cs1 = ctab[(s << 5) + 16 + l16];
          const float x1a = w[0][r], x2a = w[2][r];
          const float x1b = w[1][r], x2b = w[3][r];
          w[0][r] = x1a * cs0.x - x2a * cs0.y;
          w[2][r] = x2a * cs0.x + x1a * cs0.y;
          w[1][r] = x1b * cs1.x - x2b * cs1.y;
          w[3][r] = x2b * cs1.x + x1b * cs1.y;
        }
#pragma unroll
        for (int nt = 0; nt < 4; ++nt) {
          const int cn = n0 + wn + nt * 16 + l16;
          const int g = (((cn >> 6) & 15) << 7) + ((cn >> 10) << 6) + (cn & 63);
#pragma unroll
          for (int r = 0; r < 4; ++r)
            qfull[(size_t)(row + r) * 2048 + g] = __float2bfloat16(w[nt][r]);
        }
      }
    }
  } else {
#pragma unroll
    for (int mt = 0; mt < 4; ++mt) {
      const int row = m0 + wm + mt * 16 + quad * 4;
#pragma unroll
      for (int nt = 0; nt < 4; ++nt) {
        const int cn = n0 + wn + nt * 16 + l16;
        const f32x4 v = acc[mt][nt];
        if (cn < 1024) {
          const int g = ((cn >> 6) << 7) + (cn & 63);
#pragma unroll
          for (int r = 0; r < 4; ++r)
            kfull[(size_t)(row + r) * 2048 + g] = __float2bfloat16(v[r]);
        } else {
          const int cn2 = cn - 1024;
          const int bb = row >> 11, s0 = row & 2047;
          b16x4 pk;
          pk.a = __float2bfloat16(v[0]); pk.b = __float2bfloat16(v[1]);
          pk.c = __float2bfloat16(v[2]); pk.d = __float2bfloat16(v[3]);
          *(b16x4*)(vT + ((size_t)(bb * 2048 + cn2)) * 2048 + s0) = pk;
        }
      }
    }
  }
}

// ---------------------------------------------------------------------------
// Flash attention v10 (causal, equal-work key-split, SYNC-FREE). Block
// (bh,j): phase A = upper key-half of qt=15-j -> unnorm partial to poA + lA;
// phase B = lower half of qt=j -> unnorm into Y + lB. Every block = 17
// steps; combine in a separate merge kernel (kernel-boundary visibility).
// r8 measured: 57.3 us, occupancy flat 18%, MfmaUtil 25.7.
// ---------------------------------------------------------------------------
__device__ __forceinline__ void attn_phase(
    const bf16* __restrict__ Q, const bf16* __restrict__ Kf,
    const bf16* __restrict__ VT,
    size_t kqbase, size_t vtbase, int qt, int t0, int t1,
    bf16* __restrict__ Ks, bf16* __restrict__ VTs, bf16* __restrict__ Psw,
    f32x4 (&o)[2][8], f32x4 (&lacc)[2], const short8 ones,
    int wave, int quad, int l16, int krow, int kcol, int vrow, int vcol)
{
  const float C2 = 0.08838834764831845f * 1.4426950408889634f; // scale*log2e
  const float MNEG = -30.0f;
  const int wq0 = qt * 128 + wave * 32;        // this wave's first q row

  short8 qf[2][4];
#pragma unroll
  for (int m = 0; m < 2; ++m) {
    const bf16* qp = Q + kqbase + (size_t)(wq0 + m * 16 + l16) * 2048 + quad * 8;
#pragma unroll
    for (int kc = 0; kc < 4; ++kc) qf[m][kc] = *(const short8*)(qp + kc * 32);
  }

  short8 kg[4], vg[4];
  {
    const int kk = t0 * 64;
#pragma unroll
    for (int i = 0; i < 4; ++i)
      kg[i] = *(const short8*)(Kf + kqbase + (size_t)(kk + krow + i * 16) * 2048 + kcol);
#pragma unroll
    for (int i = 0; i < 4; ++i)
      vg[i] = *(const short8*)(VT + vtbase + (size_t)(vrow + i * 32) * 2048 + kk + vcol);
  }

  for (int t = t0; t < t1; ++t) {
    const int k0 = t * 64;
    __syncthreads();                    // all waves done reading prev tile
#pragma unroll
    for (int i = 0; i < 4; ++i) {
      const int rw = krow + i * 16;
      *(short8*)&Ks[rw * 128 + (kcol ^ ((rw & 7) * 8))] = kg[i];
    }
#pragma unroll
    for (int i = 0; i < 4; ++i) {
      const int rw = vrow + i * 32;
      *(short8*)&VTs[rw * 64 + (vcol ^ ((rw & 7) * 8))] = vg[i];
    }
    __syncthreads();                    // tile t visible
    if (t + 1 < t1) {                   // prefetch t+1 under compute
      const int kn = k0 + 64;
#pragma unroll
      for (int i = 0; i < 4; ++i)
        kg[i] = *(const short8*)(Kf + kqbase + (size_t)(kn + krow + i * 16) * 2048 + kcol);
#pragma unroll
      for (int i = 0; i < 4; ++i)
        vg[i] = *(const short8*)(VT + vtbase + (size_t)(vrow + i * 32) * 2048 + kn + vcol);
    }
    if (k0 > wq0 + 31) continue;        // wave fully masked (barriers done)

    // ---- S = Q K^T; both m-strips share each K fragment ----
    f32x4 sf[2][4];
#pragma unroll
    for (int kt = 0; kt < 4; ++kt) {
      sf[0][kt] = (f32x4){0, 0, 0, 0};
      sf[1][kt] = (f32x4){0, 0, 0, 0};
    }
#pragma unroll
    for (int kt = 0; kt < 4; ++kt) {
#pragma unroll
      for (int kc = 0; kc < 4; ++kc) {
        const short8 bfr = *(const short8*)&Ks[(kt * 16 + l16) * 128 +
                                              ((kc * 32 + quad * 8) ^ ((l16 & 7) * 8))];
        sf[0][kt] = __builtin_amdgcn_mfma_f32_16x16x32_bf16(qf[0][kc], bfr, sf[0][kt], 0, 0, 0);
        sf[1][kt] = __builtin_amdgcn_mfma_f32_16x16x32_bf16(qf[1][kc], bfr, sf[1][kt], 0, 0, 0);
      }
    }
    // ---- causal mask (diagonal tiles only) ----
#pragma unroll
    for (int m = 0; m < 2; ++m) {
      const int row0m = wq0 + m * 16 + quad * 4;
      if (k0 + 63 > row0m) {
#pragma unroll
        for (int kt = 0; kt < 4; ++kt) {
          const int col = k0 + kt * 16 + l16;
#pragma unroll
          for (int r = 0; r < 4; ++r)
            sf[m][kt][r] = (col > row0m + r) ? -3e38f : sf[m][kt][r];
        }
      }
    }
    // ---- p = exp2(s*C2 - M) -> Ps (quad-XOR swizzle: conflict-free) ----
#pragma unroll
    for (int m = 0; m < 2; ++m)
#pragma unroll
      for (int kt = 0; kt < 4; ++kt)
#pragma unroll
        for (int r = 0; r < 4; ++r) {
          const float p = fast_exp2(__builtin_fmaf(sf[m][kt][r], C2, MNEG));
          const int prow = m * 16 + quad * 4 + r;
          const int pcol = (kt * 16 + l16) ^ (quad * 16);
          Psw[prow * 64 + pcol] = __float2bfloat16(p);
        }
    asm volatile("s_waitcnt lgkmcnt(0)" ::: "memory");
    // ---- O += P V, l += P*1; V fragments shared by both strips ----
#pragma unroll
    for (int kc = 0; kc < 2; ++kc) {
      short8 ap[2];
      const int acol = (kc * 32 + quad * 8) ^ (((l16 >> 2) & 3) * 16);
      ap[0] = *(const short8*)&Psw[l16 * 64 + acol];
      lacc[0] = __builtin_amdgcn_mfma_f32_16x16x32_bf16(ap[0], ones, lacc[0], 0, 0, 0);
      ap[1] = *(const short8*)&Psw[(16 + l16) * 64 + acol];
      lacc[1] = __builtin_amdgcn_mfma_f32_16x16x32_bf16(ap[1], ones, lacc[1], 0, 0, 0);
#pragma unroll
      for (int dt = 0; dt < 8; ++dt) {
        const short8 vb = *(const short8*)&VTs[(dt * 16 + l16) * 64 +
                                              ((kc * 32 + quad * 8) ^ ((l16 & 7) * 8))];
        o[0][dt] = __builtin_amdgcn_mfma_f32_16x16x32_bf16(ap[0], vb, o[0][dt], 0, 0, 0);
        o[1][dt] = __builtin_amdgcn_mfma_f32_16x16x32_bf16(ap[1], vb, o[1][dt], 0, 0, 0);
      }
    }
  }
}

__global__ __launch_bounds__(256, 2) void attn10_kernel(
    const bf16* __restrict__ Q, const bf16* __restrict__ Kf,
    const bf16* __restrict__ VT, bf16* __restrict__ Y,
    bf16* __restrict__ poA, float* __restrict__ lA, float* __restrict__ lB)
{
  __shared__ __align__(16) bf16 Ks[64 * 128];    // [key][d], XOR-swizzled
  __shared__ __align__(16) bf16 VTs[128 * 64];   // [d][key], XOR-swizzled
  __shared__ __align__(16) bf16 Ps[4 * 32 * 64]; // per-wave P, quad-XOR-swizzled
  const int tid  = threadIdx.x;
  const int wave = tid >> 6, lane = tid & 63;
  const int quad = lane >> 4, l16 = lane & 15;
  const int bh = blockIdx.x;                     // fastest-varying -> L2 locality
  const int j  = blockIdx.y;
  const int qt_A = 15 - j;                       // phase A: upper key-half
  const int qt_B = j;                            // phase B: lower key-half
  const size_t kqbase = ((size_t)(bh >> 4) * 2048) * 2048 + (bh & 15) * 128;
  const size_t vtbase = (size_t)bh * 128 * 2048;

  short8 ones;
#pragma unroll
  for (int i = 0; i < 8; ++i) ones[i] = (short)0x3F80;   // bf16 1.0

  const int krow = tid >> 4, kcol = (tid & 15) * 8;  // K: 4 instr x 16 rows
  const int vrow = tid >> 3, vcol = (tid & 7) * 8;   // VT: 4 instr x 32 rows
  bf16* Psw = Ps + wave * (32 * 64);

  f32x4 o[2][8];
  f32x4 lacc[2];

  // ---------------- PHASE A: keys [qt_A+1, 2qt_A+2) of q-tile qt_A -------
#pragma unroll
  for (int m = 0; m < 2; ++m)
#pragma unroll
    for (int i = 0; i < 8; ++i) o[m][i] = (f32x4){0, 0, 0, 0};
  lacc[0] = (f32x4){0, 0, 0, 0};
  lacc[1] = (f32x4){0, 0, 0, 0};
  attn_phase(Q, Kf, VT, kqbase, vtbase, qt_A, qt_A + 1, 2 * qt_A + 2,
             Ks, VTs, Psw, o, lacc, ones, wave, quad, l16, krow, kcol, vrow, vcol);
  {
    bf16* po = poA + ((size_t)(bh * 16 + qt_A) << 14);
    float* pl = lA + ((bh * 16 + qt_A) << 7);
#pragma unroll
    for (int m = 0; m < 2; ++m)
#pragma unroll
      for (int r = 0; r < 4; ++r) {
        const int rl = wave * 32 + m * 16 + quad * 4 + r;
#pragma unroll
        for (int dt = 0; dt < 8; ++dt)
          po[rl * 128 + dt * 16 + l16] = __float2bfloat16(o[m][dt][r]);
        if (l16 == 0) pl[rl] = lacc[m][r];
      }
  }

  // ---------------- PHASE B: keys [0, qt_B+1) of q-tile qt_B -------------
#pragma unroll
  for (int m = 0; m < 2; ++m)
#pragma unroll
    for (int i = 0; i < 8; ++i) o[m][i] = (f32x4){0, 0, 0, 0};
  lacc[0] = (f32x4){0, 0, 0, 0};
  lacc[1] = (f32x4){0, 0, 0, 0};
  attn_phase(Q, Kf, VT, kqbase, vtbase, qt_B, 0, qt_B + 1,
             Ks, VTs, Psw, o, lacc, ones, wave, quad, l16, krow, kcol, vrow, vcol);
  {
    float* pl = lB + ((bh * 16 + qt_B) << 7);
#pragma unroll
    for (int m = 0; m < 2; ++m)
#pragma unroll
      for (int r = 0; r < 4; ++r) {
        const int rl = wave * 32 + m * 16 + quad * 4 + r;
#pragma unroll
        for (int dt = 0; dt < 8; ++dt)
          Y[kqbase + (size_t)(qt_B * 128 + rl) * 2048 + dt * 16 + l16] =
              __float2bfloat16(o[m][dt][r]);
        if (l16 == 0) pl[rl] = lacc[m][r];
      }
  }
}

// ---------------------------------------------------------------------------
// Merge: Y = (Y + poA) / (lA + lB), elementwise in place. 8 bf16/thread.
// ---------------------------------------------------------------------------
__global__ void attn_merge(bf16* __restrict__ Y, const bf16* __restrict__ poA,
                           const float* __restrict__ lA, const float* __restrict__ lB)
{
  const int t = blockIdx.x * 256 + threadIdx.x;
  const size_t e = (size_t)t * 8;                // 8.39M elems / 8
  const int col = (int)(e & 2047);
  const int row = (int)(e >> 11);                // b*2048 + s
  const int b = row >> 11, s = row & 2047;
  const int h = col >> 7, dcol = col & 127;
  const int bh = b * 16 + h, qt = s >> 7, rl = s & 127;
  const int li = ((bh * 16 + qt) << 7) + rl;
  const float inv = 1.0f / (lA[li] + lB[li]);
  const short8 va = *(const short8*)(poA + (((size_t)(bh * 16 + qt)) << 14) + rl * 128 + dcol);
  const short8 vb = *(const short8*)(Y + e);
  short8 out;
#pragma unroll
  for (int i = 0; i < 8; ++i) {
    const float fa = __bfloat162float(((const bf16*)&va)[i]);
    const float fb = __bfloat162float(((const bf16*)&vb)[i]);
    ((bf16*)&out)[i] = __float2bfloat16((fa + fb) * inv);
  }
  *(short8*)(Y + e) = out;
}

// ---------------------------------------------------------------------------
extern "C" void kernel_launch(void* const* d_in, const int* in_sizes, int n_in,
                              void* d_out, int out_size, void* d_ws, size_t ws_size,
                              hipStream_t stream)
{
  const float* x      = (const float*)d_in[0];
  const float* Wkvd   = (const float*)d_in[1];
  const float* Wqd    = (const float*)d_in[2];
  const float* Wku    = (const float*)d_in[3];
  const float* Wqu    = (const float*)d_in[4];
  const float* Wvu    = (const float*)d_in[5];
  const float* Wropek = (const float*)d_in[6];
  const float* Wropeq = (const float*)d_in[7];
  const float* Wo     = (const float*)d_in[8];

  char* ws = (char*)d_ws;
  size_t off = 0;
  auto alloc = [&](size_t elems) {
    bf16* p = (bf16*)(ws + off);
    off += ((elems * sizeof(bf16) + 255) & ~(size_t)255);
    return p;
  };
  // Region A — dead before attn; ybuf (16 MB) aliases it.
  bf16* wtX    = alloc((size_t)2048 * 2048); // Wkvd^T | Wqd^T | Wropek^T
  bf16* wtUP   = alloc((size_t)3072 * 512);  // Wku^T | Wvu^T
  bf16* wtQcat = alloc((size_t)2048 * 512);  // Wqu^T | Wropeq^T
  bf16* latcat = alloc((size_t)4096 * 1024);
  // end region A (21 MB)
  bf16* wt_o   = alloc((size_t)2048 * 2048);
  bf16* xbf    = alloc((size_t)4096 * 2048);
  bf16* qfull  = alloc((size_t)4096 * 2048);
  bf16* kfull  = alloc((size_t)4096 * 2048);
  float2* ctab = (float2*)alloc((size_t)65536 * 4);  // 512 KB cos/sin table
  bf16* ybuf   = (bf16*)ws;
  bf16* vT     = (bf16*)d_out;
  // attn10 partials in dead-at-attn regions: poA = xbf (dead after gemm1);
  // lA/lB in latcat tail [16MB, 16.5MB), outside ybuf's [0,16MB) alias.
  bf16*  poA = xbf;
  float* lA  = (float*)(ws + 16777216);
  float* lB  = (float*)(ws + 16777216 + 262144);
  (void)ws_size; (void)in_sizes; (void)n_in; (void)out_size;

  PrepArgs pa;
  const float* srcs[8] = {Wkvd, Wqd, Wropek, Wku, Wvu, Wqu, Wropeq, Wo};
  bf16* dsts[8] = {wtX, wtX + (size_t)512 * 2048, wtX + (size_t)1024 * 2048,
                   wtUP, wtUP + (size_t)1024 * 512,
                   wtQcat, wtQcat + (size_t)1024 * 512, wt_o};
  const int Rs[8] = {2048, 2048, 2048, 512, 512, 512, 512, 2048};
  const int Cs[8] = {512, 512, 1024, 1024, 2048, 1024, 1024, 2048};
  int cum = 0;
  for (int e = 0; e < 8; ++e) {
    pa.src[e] = srcs[e]; pa.dst[e] = dsts[e]; pa.R[e] = Rs[e]; pa.C[e] = Cs[e];
    cum += (Rs[e] >> 5) * (Cs[e] >> 5);
    pa.cum[e] = cum;
  }
  // cvt + rope-table + all transposes in ONE launch
  prep_all<<<8448 + cum, 256, 0, stream>>>(x, xbf, ctab, pa);

  // latcat = x @ [W_kv_d | W_q_d]  AND  k_rope = x @ W_rope_k (RoPE fused)
  gemm_bt<bf16, 4><<<dim3(16, 32), 256, 0, stream>>>(xbf, 2048, wtX, latcat, kfull, 1024, 2048, ctab);
  // k_nope+vT AND q-interleave (q_rope RoPE fused), single launch
  gemm_up_fused<<<dim3(40, 32), 256, 0, stream>>>(latcat, wtUP, wtQcat, vT, kfull, qfull, ctab);

  attn10_kernel<<<dim3(32, 16), 256, 0, stream>>>(qfull, kfull, vT, ybuf, poA, lA, lB);
  attn_merge<<<4096, 256, 0, stream>>>(ybuf, poA, lA, lB);

  // out = y @ W_o, SPLIT-K (z=2): zero d_out (vT role dead after attn),
  // each K-half atomicAdds f32 partial sums.
  hipMemsetAsync(d_out, 0, (size_t)4096 * 2048 * sizeof(float), stream);
  gemm_bt<float, 0><<<dim3(16, 32, 2), 256, 0, stream>>>(ybuf, 2048, wt_o, (float*)d_out, (bf16*)nullptr, 2048, 2048, ctab);
}

// Round 10
// 336.247 us; speedup vs baseline: 1.0770x; 1.0770x over previous
//
#include <hip/hip_runtime.h>
#include <hip/hip_bf16.h>

typedef __hip_bfloat16 bf16;
typedef __attribute__((ext_vector_type(8))) short short8;
typedef __attribute__((ext_vector_type(4))) float f32x4;

#define AS1 __attribute__((address_space(1)))
#define AS3 __attribute__((address_space(3)))

__device__ __forceinline__ void gload_lds16(const bf16* gp, bf16* lp) {
  __builtin_amdgcn_global_load_lds((const AS1 void*)gp, (AS3 void*)lp, 16, 0, 0);
}

__device__ __forceinline__ float fast_exp2(float x) {
#if __has_builtin(__builtin_amdgcn_exp2f)
  return __builtin_amdgcn_exp2f(x);
#else
  return exp2f(x);
#endif
}

__device__ __forceinline__ void store_c(bf16* C, size_t idx, float v) { C[idx] = __float2bfloat16(v); }
__device__ __forceinline__ void store_c(float* C, size_t idx, float v) { C[idx] = v; }

struct __align__(8) b16x4 { bf16 a, b, c, d; };

// ---------------------------------------------------------------------------
// prep_all: ONE kernel for (a) fp32->bf16 convert of x, (b) RoPE cos/sin
// table, (c) all 8 weight transposes. Block-ranged dispatch.
// r5 lesson: trig calls live ONLY in the tab range.
// ---------------------------------------------------------------------------
struct PrepArgs {
  const float* src[8];
  bf16* dst[8];
  int R[8], C[8], cum[8];
};

__global__ void prep_all(const float* __restrict__ x, bf16* __restrict__ xbf,
                         float2* __restrict__ ctab, PrepArgs a)
{
  const int blk = blockIdx.x;
  const int tid = threadIdx.x;
  if (blk < 8192) {                       // ---- cvt x -> xbf ----
    const int i = (blk * 256 + tid) * 4;
    const float4 v = *(const float4*)(x + i);
    xbf[i + 0] = __float2bfloat16(v.x);
    xbf[i + 1] = __float2bfloat16(v.y);
    xbf[i + 2] = __float2bfloat16(v.z);
    xbf[i + 3] = __float2bfloat16(v.w);
    return;
  }
  if (blk < 8448) {                       // ---- RoPE table ----
    const int idx = (blk - 8192) * 256 + tid;   // 65536 entries
    const int i = idx & 31;
    const int s = idx >> 5;
    const float inv = fast_exp2(-(float)i * 0.41524101186092029f);
    const float ang = (float)s * inv;
    ctab[idx] = make_float2(cosf(ang), sinf(ang));
    return;
  }
  // ---- weight transposes (fp32 [R][C] -> bf16 [C][R]) ----
  __shared__ bf16 t[32][33];
  const int pb = blk - 8448;
  int e = 0;
  while (e < 7 && pb >= a.cum[e]) ++e;
  const int lt = pb - (e ? a.cum[e - 1] : 0);
  const int R = a.R[e], C = a.C[e];
  const int tpr = C >> 5;
  const int bx = lt % tpr, by = lt / tpr;
  const float* in = a.src[e];
  bf16* out = a.dst[e];
  const int c0 = bx * 32, r0 = by * 32;
  const int tx = tid & 31, ty = tid >> 5;
  for (int i = 0; i < 4; ++i)
    t[ty + 8 * i][tx] = __float2bfloat16(in[(size_t)(r0 + ty + 8 * i) * C + c0 + tx]);
  __syncthreads();
  for (int i = 0; i < 4; ++i)
    out[(size_t)(c0 + ty + 8 * i) * R + r0 + tx] = t[tx][ty + 8 * i];
}

// ---------------------------------------------------------------------------
// bf16 GEMM, C = A @ B with B transposed (Bt[N][K]). r10: BM=128 x BN=64
// tiles, 4 waves each owning 32 rows x all 64 cols (4m x 1n). Grid (N/64,
// M/128) = 1024 blocks = 4/CU (vs 2/CU at BN=128) — attacks the latency-
// exposed regime directly (r7: waitcnt games null; r9: split-K output-RMW
// net-negative). LDS 24 KB dbuf; 3 gload_lds/thread/step, vmcnt(3).
// Wave layout 4m x 1n preserves rope-pair (nt,nt+2) same-thread property.
// MODE 4: n0<1024 -> latcat; n0>=1024 -> k_rope with RoPE fused via ctab.
// MODE 0: plain f32 store.
// ---------------------------------------------------------------------------
template <typename CT, int MODE>
__global__ void gemm_bt(const bf16* __restrict__ A, int lda,
                        const bf16* __restrict__ Bt,
                        CT* __restrict__ C, bf16* __restrict__ C2, int ldc,
                        int K, const float2* __restrict__ ctab)
{
  __shared__ __align__(16) bf16 As[2][128 * 32];
  __shared__ __align__(16) bf16 Bs[2][64 * 32];
  const int tid  = threadIdx.x;
  const int wave = tid >> 6, lane = tid & 63;
  const int quad = lane >> 4, l16 = lane & 15;
  const int m0 = blockIdx.y * 128, n0 = blockIdx.x * 64;
  const int wm = wave * 32;

  f32x4 acc[2][4];
#pragma unroll
  for (int i = 0; i < 2; ++i)
#pragma unroll
    for (int j = 0; j < 4; ++j) acc[i][j] = (f32x4){0.f, 0.f, 0.f, 0.f};

  const int r1  = tid >> 2;               // A rows 0..63 (+64 on 2nd instr)
  const int ks1 = (tid & 3) * 8;

  gload_lds16(A  + (size_t)(m0 + r1)      * lda + ks1, &As[0][tid * 8]);
  gload_lds16(A  + (size_t)(m0 + r1 + 64) * lda + ks1, &As[0][(tid + 256) * 8]);
  gload_lds16(Bt + (size_t)(n0 + r1)      * K   + ks1, &Bs[0][tid * 8]);

  int cur = 0;
  for (int k0 = 0; k0 < K; k0 += 32) {
    if (k0 + 32 < K) {                  // prefetch next tile into buf^1
      const int kn = k0 + 32;
      const int nxt = cur ^ 1;
      gload_lds16(A  + (size_t)(m0 + r1)      * lda + kn + ks1, &As[nxt][tid * 8]);
      gload_lds16(A  + (size_t)(m0 + r1 + 64) * lda + kn + ks1, &As[nxt][(tid + 256) * 8]);
      gload_lds16(Bt + (size_t)(n0 + r1)      * K   + kn + ks1, &Bs[nxt][tid * 8]);
      asm volatile("s_waitcnt vmcnt(3)" ::: "memory");   // current tile done
    } else {
      asm volatile("s_waitcnt vmcnt(0)" ::: "memory");
    }
    __builtin_amdgcn_s_barrier();

    short8 af[2], bf_[4];
#pragma unroll
    for (int mt = 0; mt < 2; ++mt)
      af[mt] = *(const short8*)&As[cur][(wm + mt * 16 + l16) * 32 + quad * 8];
#pragma unroll
    for (int nt = 0; nt < 4; ++nt)
      bf_[nt] = *(const short8*)&Bs[cur][(nt * 16 + l16) * 32 + quad * 8];
#pragma unroll
    for (int mt = 0; mt < 2; ++mt)
#pragma unroll
      for (int nt = 0; nt < 4; ++nt)
        acc[mt][nt] = __builtin_amdgcn_mfma_f32_16x16x32_bf16(af[mt], bf_[nt], acc[mt][nt], 0, 0, 0);
    __builtin_amdgcn_s_barrier();
    cur ^= 1;
  }

  if (MODE == 0) {
#pragma unroll
    for (int mt = 0; mt < 2; ++mt) {
      const int row = m0 + wm + mt * 16 + quad * 4;
#pragma unroll
      for (int nt = 0; nt < 4; ++nt) {
        const int cn = n0 + nt * 16 + l16;
        const f32x4 v = acc[mt][nt];
#pragma unroll
        for (int r = 0; r < 4; ++r)
          store_c(C, (size_t)(row + r) * ldc + cn, v[r]);
      }
    }
  } else if (MODE == 4) {
    if (n0 < 1024) {
      // latcat path (whole block has cn < 1024)
#pragma unroll
      for (int mt = 0; mt < 2; ++mt) {
        const int row = m0 + wm + mt * 16 + quad * 4;
#pragma unroll
        for (int nt = 0; nt < 4; ++nt) {
          const int cn = n0 + nt * 16 + l16;
          const f32x4 v = acc[mt][nt];
#pragma unroll
          for (int r = 0; r < 4; ++r)
            store_c(C, (size_t)(row + r) * 1024 + cn, v[r]);
        }
      }
    } else {
      // k_rope path: RoPE via table lookup (no trig calls -> no spills)
#pragma unroll
      for (int mt = 0; mt < 2; ++mt) {
        const int row = m0 + wm + mt * 16 + quad * 4;
        f32x4 w[4];
#pragma unroll
        for (int nt = 0; nt < 4; ++nt) w[nt] = acc[mt][nt];
#pragma unroll
        for (int r = 0; r < 4; ++r) {
          const int s = (row + r) & 2047;
          const float2 cs0 = ctab[(s << 5) + l16];
          const float2 cs1 = ctab[(s << 5) + 16 + l16];
          const float x1a = w[0][r], x2a = w[2][r];
          const float x1b = w[1][r], x2b = w[3][r];
          w[0][r] = x1a * cs0.x - x2a * cs0.y;
          w[2][r] = x2a * cs0.x + x1a * cs0.y;
          w[1][r] = x1b * cs1.x - x2b * cs1.y;
          w[3][r] = x2b * cs1.x + x1b * cs1.y;
        }
#pragma unroll
        for (int nt = 0; nt < 4; ++nt) {
          const int cn2 = n0 + nt * 16 + l16 - 1024;
          const int g = ((cn2 >> 6) << 7) + 64 + (cn2 & 63);
#pragma unroll
          for (int r = 0; r < 4; ++r)
            C2[(size_t)(row + r) * 2048 + g] = __float2bfloat16(w[nt][r]);
        }
      }
    }
  }
}

// ---------------------------------------------------------------------------
// Fused up-projection GEMM: k_nope+vT (N=3072) and q-interleave (N=2048).
// K=512, lda=1024. grid=(40,32) = 1280 blocks = 5/CU — occupancy already
// fine; unchanged (128x128 tiles, r6 dbuf staging).
// ---------------------------------------------------------------------------
__global__ void gemm_up_fused(const bf16* __restrict__ latcat,
                              const bf16* __restrict__ wtUP,
                              const bf16* __restrict__ wtQcat,
                              bf16* __restrict__ vT, bf16* __restrict__ kfull,
                              bf16* __restrict__ qfull,
                              const float2* __restrict__ ctab)
{
  const bool is2 = (blockIdx.x >= 24);
  const bf16* A  = latcat + (is2 ? 512 : 0);
  const bf16* Bt = is2 ? wtQcat : wtUP;
  const int n0 = (is2 ? (int)blockIdx.x - 24 : (int)blockIdx.x) * 128;
  const int K = 512, lda = 1024;

  __shared__ __align__(16) bf16 As[2][128 * 32];
  __shared__ __align__(16) bf16 Bs[2][128 * 32];
  const int tid  = threadIdx.x;
  const int wave = tid >> 6, lane = tid & 63;
  const int quad = lane >> 4, l16 = lane & 15;
  const int m0 = blockIdx.y * 128;
  const int wm = (wave >> 1) * 64, wn = (wave & 1) * 64;

  f32x4 acc[4][4];
#pragma unroll
  for (int i = 0; i < 4; ++i)
#pragma unroll
    for (int j = 0; j < 4; ++j) acc[i][j] = (f32x4){0.f, 0.f, 0.f, 0.f};

  const int r1  = tid >> 2;
  const int ks1 = (tid & 3) * 8;

  gload_lds16(A  + (size_t)(m0 + r1)      * lda + ks1, &As[0][tid * 8]);
  gload_lds16(A  + (size_t)(m0 + r1 + 64) * lda + ks1, &As[0][(tid + 256) * 8]);
  gload_lds16(Bt + (size_t)(n0 + r1)      * K   + ks1, &Bs[0][tid * 8]);
  gload_lds16(Bt + (size_t)(n0 + r1 + 64) * K   + ks1, &Bs[0][(tid + 256) * 8]);

  int cur = 0;
  for (int k0 = 0; k0 < K; k0 += 32) {
    if (k0 + 32 < K) {
      const int kn = k0 + 32;
      const int nxt = cur ^ 1;
      gload_lds16(A  + (size_t)(m0 + r1)      * lda + kn + ks1, &As[nxt][tid * 8]);
      gload_lds16(A  + (size_t)(m0 + r1 + 64) * lda + kn + ks1, &As[nxt][(tid + 256) * 8]);
      gload_lds16(Bt + (size_t)(n0 + r1)      * K   + kn + ks1, &Bs[nxt][tid * 8]);
      gload_lds16(Bt + (size_t)(n0 + r1 + 64) * K   + kn + ks1, &Bs[nxt][(tid + 256) * 8]);
      asm volatile("s_waitcnt vmcnt(4)" ::: "memory");
    } else {
      asm volatile("s_waitcnt vmcnt(0)" ::: "memory");
    }
    __builtin_amdgcn_s_barrier();

    short8 af[4], bf_[4];
#pragma unroll
    for (int mt = 0; mt < 4; ++mt)
      af[mt] = *(const short8*)&As[cur][(wm + mt * 16 + l16) * 32 + quad * 8];
#pragma unroll
    for (int nt = 0; nt < 4; ++nt)
      bf_[nt] = *(const short8*)&Bs[cur][(wn + nt * 16 + l16) * 32 + quad * 8];
#pragma unroll
    for (int mt = 0; mt < 4; ++mt)
#pragma unroll
      for (int nt = 0; nt < 4; ++nt)
        acc[mt][nt] = __builtin_amdgcn_mfma_f32_16x16x32_bf16(af[mt], bf_[nt], acc[mt][nt], 0, 0, 0);
    __builtin_amdgcn_s_barrier();
    cur ^= 1;
  }

  if (is2) {
    if (n0 < 1024) {
#pragma unroll
      for (int mt = 0; mt < 4; ++mt) {
        const int row = m0 + wm + mt * 16 + quad * 4;
#pragma unroll
        for (int nt = 0; nt < 4; ++nt) {
          const int cn = n0 + wn + nt * 16 + l16;
          const int g = (((cn >> 6) & 15) << 7) + ((cn >> 10) << 6) + (cn & 63);
          const f32x4 v = acc[mt][nt];
#pragma unroll
          for (int r = 0; r < 4; ++r)
            qfull[(size_t)(row + r) * 2048 + g] = __float2bfloat16(v[r]);
        }
      }
    } else {
      // q_rope half: RoPE via table lookup, then interleave store
#pragma unroll
      for (int mt = 0; mt < 4; ++mt) {
        const int row = m0 + wm + mt * 16 + quad * 4;
        f32x4 w[4];
#pragma unroll
        for (int nt = 0; nt < 4; ++nt) w[nt] = acc[mt][nt];
#pragma unroll
        for (int r = 0; r < 4; ++r) {
          const int s = (row + r) & 2047;
          const float2 cs0 = ctab[(s << 5) + l16];
          const float2 cs1 = ctab[(s << 5) + 16 + l16];
          const float x1a = w[0][r], x2a = w[2][r];
          const float x1b = w[1][r], x2b = w[3][r];
          w[0][r] = x1a * cs0.x - x2a * cs0.y;
          w[2][r] = x2a * cs0.x + x1a * cs0.y;
          w[1][r] = x1b * cs1.x - x2b * cs1.y;
          w[3][r] = x2b * cs1.x + x1b * cs1.y;
        }
#pragma unroll
        for (int nt = 0; nt < 4; ++nt) {
          const int cn = n0 + wn + nt * 16 + l16;
          const int g = (((cn >> 6) & 15) << 7) + ((cn >> 10) << 6) + (cn & 63);
#pragma unroll
          for (int r = 0; r < 4; ++r)
            qfull[(size_t)(row + r) * 2048 + g] = __float2bfloat16(w[nt][r]);
        }
      }
    }
  } else {
#pragma unroll
    for (int mt = 0; mt < 4; ++mt) {
      const int row = m0 + wm + mt * 16 + quad * 4;
#pragma unroll
      for (int nt = 0; nt < 4; ++nt) {
        const int cn = n0 + wn + nt * 16 + l16;
        const f32x4 v = acc[mt][nt];
        if (cn < 1024) {
          const int g = ((cn >> 6) << 7) + (cn & 63);
#pragma unroll
          for (int r = 0; r < 4; ++r)
            kfull[(size_t)(row + r) * 2048 + g] = __float2bfloat16(v[r]);
        } else {
          const int cn2 = cn - 1024;
          const int bb = row >> 11, s0 = row & 2047;
          b16x4 pk;
          pk.a = __float2bfloat16(v[0]); pk.b = __float2bfloat16(v[1]);
          pk.c = __float2bfloat16(v[2]); pk.d = __float2bfloat16(v[3]);
          *(b16x4*)(vT + ((size_t)(bb * 2048 + cn2)) * 2048 + s0) = pk;
        }
      }
    }
  }
}

// ---------------------------------------------------------------------------
// Flash attention v10 (causal, equal-work key-split, SYNC-FREE). Block
// (bh,j): phase A = upper key-half of qt=15-j -> unnorm partial to poA + lA;
// phase B = lower half of qt=j -> unnorm into Y + lB. Every block = 17
// steps; combine in a separate merge kernel (kernel-boundary visibility).
// r8 measured: 57.3 us, occupancy flat 18%, MfmaUtil 25.7.
// ---------------------------------------------------------------------------
__device__ __forceinline__ void attn_phase(
    const bf16* __restrict__ Q, const bf16* __restrict__ Kf,
    const bf16* __restrict__ VT,
    size_t kqbase, size_t vtbase, int qt, int t0, int t1,
    bf16* __restrict__ Ks, bf16* __restrict__ VTs, bf16* __restrict__ Psw,
    f32x4 (&o)[2][8], f32x4 (&lacc)[2], const short8 ones,
    int wave, int quad, int l16, int krow, int kcol, int vrow, int vcol)
{
  const float C2 = 0.08838834764831845f * 1.4426950408889634f; // scale*log2e
  const float MNEG = -30.0f;
  const int wq0 = qt * 128 + wave * 32;        // this wave's first q row

  short8 qf[2][4];
#pragma unroll
  for (int m = 0; m < 2; ++m) {
    const bf16* qp = Q + kqbase + (size_t)(wq0 + m * 16 + l16) * 2048 + quad * 8;
#pragma unroll
    for (int kc = 0; kc < 4; ++kc) qf[m][kc] = *(const short8*)(qp + kc * 32);
  }

  short8 kg[4], vg[4];
  {
    const int kk = t0 * 64;
#pragma unroll
    for (int i = 0; i < 4; ++i)
      kg[i] = *(const short8*)(Kf + kqbase + (size_t)(kk + krow + i * 16) * 2048 + kcol);
#pragma unroll
    for (int i = 0; i < 4; ++i)
      vg[i] = *(const short8*)(VT + vtbase + (size_t)(vrow + i * 32) * 2048 + kk + vcol);
  }

  for (int t = t0; t < t1; ++t) {
    const int k0 = t * 64;
    __syncthreads();                    // all waves done reading prev tile
#pragma unroll
    for (int i = 0; i < 4; ++i) {
      const int rw = krow + i * 16;
      *(short8*)&Ks[rw * 128 + (kcol ^ ((rw & 7) * 8))] = kg[i];
    }
#pragma unroll
    for (int i = 0; i < 4; ++i) {
      const int rw = vrow + i * 32;
      *(short8*)&VTs[rw * 64 + (vcol ^ ((rw & 7) * 8))] = vg[i];
    }
    __syncthreads();                    // tile t visible
    if (t + 1 < t1) {                   // prefetch t+1 under compute
      const int kn = k0 + 64;
#pragma unroll
      for (int i = 0; i < 4; ++i)
        kg[i] = *(const short8*)(Kf + kqbase + (size_t)(kn + krow + i * 16) * 2048 + kcol);
#pragma unroll
      for (int i = 0; i < 4; ++i)
        vg[i] = *(const short8*)(VT + vtbase + (size_t)(vrow + i * 32) * 2048 + kn + vcol);
    }
    if (k0 > wq0 + 31) continue;        // wave fully masked (barriers done)

    // ---- S = Q K^T; both m-strips share each K fragment ----
    f32x4 sf[2][4];
#pragma unroll
    for (int kt = 0; kt < 4; ++kt) {
      sf[0][kt] = (f32x4){0, 0, 0, 0};
      sf[1][kt] = (f32x4){0, 0, 0, 0};
    }
#pragma unroll
    for (int kt = 0; kt < 4; ++kt) {
#pragma unroll
      for (int kc = 0; kc < 4; ++kc) {
        const short8 bfr = *(const short8*)&Ks[(kt * 16 + l16) * 128 +
                                              ((kc * 32 + quad * 8) ^ ((l16 & 7) * 8))];
        sf[0][kt] = __builtin_amdgcn_mfma_f32_16x16x32_bf16(qf[0][kc], bfr, sf[0][kt], 0, 0, 0);
        sf[1][kt] = __builtin_amdgcn_mfma_f32_16x16x32_bf16(qf[1][kc], bfr, sf[1][kt], 0, 0, 0);
      }
    }
    // ---- causal mask (diagonal tiles only) ----
#pragma unroll
    for (int m = 0; m < 2; ++m) {
      const int row0m = wq0 + m * 16 + quad * 4;
      if (k0 + 63 > row0m) {
#pragma unroll
        for (int kt = 0; kt < 4; ++kt) {
          const int col = k0 + kt * 16 + l16;
#pragma unroll
          for (int r = 0; r < 4; ++r)
            sf[m][kt][r] = (col > row0m + r) ? -3e38f : sf[m][kt][r];
        }
      }
    }
    // ---- p = exp2(s*C2 - M) -> Ps (quad-XOR swizzle: conflict-free) ----
#pragma unroll
    for (int m = 0; m < 2; ++m)
#pragma unroll
      for (int kt = 0; kt < 4; ++kt)
#pragma unroll
        for (int r = 0; r < 4; ++r) {
          const float p = fast_exp2(__builtin_fmaf(sf[m][kt][r], C2, MNEG));
          const int prow = m * 16 + quad * 4 + r;
          const int pcol = (kt * 16 + l16) ^ (quad * 16);
          Psw[prow * 64 + pcol] = __float2bfloat16(p);
        }
    asm volatile("s_waitcnt lgkmcnt(0)" ::: "memory");
    // ---- O += P V, l += P*1; V fragments shared by both strips ----
#pragma unroll
    for (int kc = 0; kc < 2; ++kc) {
      short8 ap[2];
      const int acol = (kc * 32 + quad * 8) ^ (((l16 >> 2) & 3) * 16);
      ap[0] = *(const short8*)&Psw[l16 * 64 + acol];
      lacc[0] = __builtin_amdgcn_mfma_f32_16x16x32_bf16(ap[0], ones, lacc[0], 0, 0, 0);
      ap[1] = *(const short8*)&Psw[(16 + l16) * 64 + acol];
      lacc[1] = __builtin_amdgcn_mfma_f32_16x16x32_bf16(ap[1], ones, lacc[1], 0, 0, 0);
#pragma unroll
      for (int dt = 0; dt < 8; ++dt) {
        const short8 vb = *(const short8*)&VTs[(dt * 16 + l16) * 64 +
                                              ((kc * 32 + quad * 8) ^ ((l16 & 7) * 8))];
        o[0][dt] = __builtin_amdgcn_mfma_f32_16x16x32_bf16(ap[0], vb, o[0][dt], 0, 0, 0);
        o[1][dt] = __builtin_amdgcn_mfma_f32_16x16x32_bf16(ap[1], vb, o[1][dt], 0, 0, 0);
      }
    }
  }
}

__global__ __launch_bounds__(256, 2) void attn10_kernel(
    const bf16* __restrict__ Q, const bf16* __restrict__ Kf,
    const bf16* __restrict__ VT, bf16* __restrict__ Y,
    bf16* __restrict__ poA, float* __restrict__ lA, float* __restrict__ lB)
{
  __shared__ __align__(16) bf16 Ks[64 * 128];    // [key][d], XOR-swizzled
  __shared__ __align__(16) bf16 VTs[128 * 64];   // [d][key], XOR-swizzled
  __shared__ __align__(16) bf16 Ps[4 * 32 * 64]; // per-wave P, quad-XOR-swizzled
  const int tid  = threadIdx.x;
  const int wave = tid >> 6, lane = tid & 63;
  const int quad = lane >> 4, l16 = lane & 15;
  const int bh = blockIdx.x;                     // fastest-varying -> L2 locality
  const int j  = blockIdx.y;
  const int qt_A = 15 - j;                       // phase A: upper key-half
  const int qt_B = j;                            // phase B: lower key-half
  const size_t kqbase = ((size_t)(bh >> 4) * 2048) * 2048 + (bh & 15) * 128;
  const size_t vtbase = (size_t)bh * 128 * 2048;

  short8 ones;
#pragma unroll
  for (int i = 0; i < 8; ++i) ones[i] = (short)0x3F80;   // bf16 1.0

  const int krow = tid >> 4, kcol = (tid & 15) * 8;  // K: 4 instr x 16 rows
  const int vrow = tid >> 3, vcol = (tid & 7) * 8;   // VT: 4 instr x 32 rows
  bf16* Psw = Ps + wave * (32 * 64);

  f32x4 o[2][8];
  f32x4 lacc[2];

  // ---------------- PHASE A: keys [qt_A+1, 2qt_A+2) of q-tile qt_A -------
#pragma unroll
  for (int m = 0; m < 2; ++m)
#pragma unroll
    for (int i = 0; i < 8; ++i) o[m][i] = (f32x4){0, 0, 0, 0};
  lacc[0] = (f32x4){0, 0, 0, 0};
  lacc[1] = (f32x4){0, 0, 0, 0};
  attn_phase(Q, Kf, VT, kqbase, vtbase, qt_A, qt_A + 1, 2 * qt_A + 2,
             Ks, VTs, Psw, o, lacc, ones, wave, quad, l16, krow, kcol, vrow, vcol);
  {
    bf16* po = poA + ((size_t)(bh * 16 + qt_A) << 14);
    float* pl = lA + ((bh * 16 + qt_A) << 7);
#pragma unroll
    for (int m = 0; m < 2; ++m)
#pragma unroll
      for (int r = 0; r < 4; ++r) {
        const int rl = wave * 32 + m * 16 + quad * 4 + r;
#pragma unroll
        for (int dt = 0; dt < 8; ++dt)
          po[rl * 128 + dt * 16 + l16] = __float2bfloat16(o[m][dt][r]);
        if (l16 == 0) pl[rl] = lacc[m][r];
      }
  }

  // ---------------- PHASE B: keys [0, qt_B+1) of q-tile qt_B -------------
#pragma unroll
  for (int m = 0; m < 2; ++m)
#pragma unroll
    for (int i = 0; i < 8; ++i) o[m][i] = (f32x4){0, 0, 0, 0};
  lacc[0] = (f32x4){0, 0, 0, 0};
  lacc[1] = (f32x4){0, 0, 0, 0};
  attn_phase(Q, Kf, VT, kqbase, vtbase, qt_B, 0, qt_B + 1,
             Ks, VTs, Psw, o, lacc, ones, wave, quad, l16, krow, kcol, vrow, vcol);
  {
    float* pl = lB + ((bh * 16 + qt_B) << 7);
#pragma unroll
    for (int m = 0; m < 2; ++m)
#pragma unroll
      for (int r = 0; r < 4; ++r) {
        const int rl = wave * 32 + m * 16 + quad * 4 + r;
#pragma unroll
        for (int dt = 0; dt < 8; ++dt)
          Y[kqbase + (size_t)(qt_B * 128 + rl) * 2048 + dt * 16 + l16] =
              __float2bfloat16(o[m][dt][r]);
        if (l16 == 0) pl[rl] = lacc[m][r];
      }
  }
}

// ---------------------------------------------------------------------------
// Merge: Y = (Y + poA) / (lA + lB), elementwise in place. 8 bf16/thread.
// ---------------------------------------------------------------------------
__global__ void attn_merge(bf16* __restrict__ Y, const bf16* __restrict__ poA,
                           const float* __restrict__ lA, const float* __restrict__ lB)
{
  const int t = blockIdx.x * 256 + threadIdx.x;
  const size_t e = (size_t)t * 8;                // 8.39M elems / 8
  const int col = (int)(e & 2047);
  const int row = (int)(e >> 11);                // b*2048 + s
  const int b = row >> 11, s = row & 2047;
  const int h = col >> 7, dcol = col & 127;
  const int bh = b * 16 + h, qt = s >> 7, rl = s & 127;
  const int li = ((bh * 16 + qt) << 7) + rl;
  const float inv = 1.0f / (lA[li] + lB[li]);
  const short8 va = *(const short8*)(poA + (((size_t)(bh * 16 + qt)) << 14) + rl * 128 + dcol);
  const short8 vb = *(const short8*)(Y + e);
  short8 out;
#pragma unroll
  for (int i = 0; i < 8; ++i) {
    const float fa = __bfloat162float(((const bf16*)&va)[i]);
    const float fb = __bfloat162float(((const bf16*)&vb)[i]);
    ((bf16*)&out)[i] = __float2bfloat16((fa + fb) * inv);
  }
  *(short8*)(Y + e) = out;
}

// ---------------------------------------------------------------------------
extern "C" void kernel_launch(void* const* d_in, const int* in_sizes, int n_in,
                              void* d_out, int out_size, void* d_ws, size_t ws_size,
                              hipStream_t stream)
{
  const float* x      = (const float*)d_in[0];
  const float* Wkvd   = (const float*)d_in[1];
  const float* Wqd    = (const float*)d_in[2];
  const float* Wku    = (const float*)d_in[3];
  const float* Wqu    = (const float*)d_in[4];
  const float* Wvu    = (const float*)d_in[5];
  const float* Wropek = (const float*)d_in[6];
  const float* Wropeq = (const float*)d_in[7];
  const float* Wo     = (const float*)d_in[8];

  char* ws = (char*)d_ws;
  size_t off = 0;
  auto alloc = [&](size_t elems) {
    bf16* p = (bf16*)(ws + off);
    off += ((elems * sizeof(bf16) + 255) & ~(size_t)255);
    return p;
  };
  // Region A — dead before attn; ybuf (16 MB) aliases it.
  bf16* wtX    = alloc((size_t)2048 * 2048); // Wkvd^T | Wqd^T | Wropek^T
  bf16* wtUP   = alloc((size_t)3072 * 512);  // Wku^T | Wvu^T
  bf16* wtQcat = alloc((size_t)2048 * 512);  // Wqu^T | Wropeq^T
  bf16* latcat = alloc((size_t)4096 * 1024);
  // end region A (21 MB)
  bf16* wt_o   = alloc((size_t)2048 * 2048);
  bf16* xbf    = alloc((size_t)4096 * 2048);
  bf16* qfull  = alloc((size_t)4096 * 2048);
  bf16* kfull  = alloc((size_t)4096 * 2048);
  float2* ctab = (float2*)alloc((size_t)65536 * 4);  // 512 KB cos/sin table
  bf16* ybuf   = (bf16*)ws;
  bf16* vT     = (bf16*)d_out;
  // attn10 partials in dead-at-attn regions: poA = xbf (dead after gemm1);
  // lA/lB in latcat tail [16MB, 16.5MB), outside ybuf's [0,16MB) alias.
  bf16*  poA = xbf;
  float* lA  = (float*)(ws + 16777216);
  float* lB  = (float*)(ws + 16777216 + 262144);
  (void)ws_size; (void)in_sizes; (void)n_in; (void)out_size;

  PrepArgs pa;
  const float* srcs[8] = {Wkvd, Wqd, Wropek, Wku, Wvu, Wqu, Wropeq, Wo};
  bf16* dsts[8] = {wtX, wtX + (size_t)512 * 2048, wtX + (size_t)1024 * 2048,
                   wtUP, wtUP + (size_t)1024 * 512,
                   wtQcat, wtQcat + (size_t)1024 * 512, wt_o};
  const int Rs[8] = {2048, 2048, 2048, 512, 512, 512, 512, 2048};
  const int Cs[8] = {512, 512, 1024, 1024, 2048, 1024, 1024, 2048};
  int cum = 0;
  for (int e = 0; e < 8; ++e) {
    pa.src[e] = srcs[e]; pa.dst[e] = dsts[e]; pa.R[e] = Rs[e]; pa.C[e] = Cs[e];
    cum += (Rs[e] >> 5) * (Cs[e] >> 5);
    pa.cum[e] = cum;
  }
  // cvt + rope-table + all transposes in ONE launch
  prep_all<<<8448 + cum, 256, 0, stream>>>(x, xbf, ctab, pa);

  // latcat = x @ [W_kv_d | W_q_d]  AND  k_rope = x @ W_rope_k (RoPE fused)
  gemm_bt<bf16, 4><<<dim3(32, 32), 256, 0, stream>>>(xbf, 2048, wtX, latcat, kfull, 1024, 2048, ctab);
  // k_nope+vT AND q-interleave (q_rope RoPE fused), single launch
  gemm_up_fused<<<dim3(40, 32), 256, 0, stream>>>(latcat, wtUP, wtQcat, vT, kfull, qfull, ctab);

  attn10_kernel<<<dim3(32, 16), 256, 0, stream>>>(qfull, kfull, vT, ybuf, poA, lA, lB);
  attn_merge<<<4096, 256, 0, stream>>>(ybuf, poA, lA, lB);

  // out = y @ W_o (plain f32 store; r9 split-K atomics reverted)
  gemm_bt<float, 0><<<dim3(32, 32), 256, 0, stream>>>(ybuf, 2048, wt_o, (float*)d_out, (bf16*)nullptr, 2048, 2048, ctab);
}

// Round 12
// 319.429 us; speedup vs baseline: 1.1338x; 1.0527x over previous
//
#include <hip/hip_runtime.h>
#include <hip/hip_bf16.h>

typedef __hip_bfloat16 bf16;
typedef __attribute__((ext_vector_type(8))) short short8;
typedef __attribute__((ext_vector_type(4))) float f32x4;

#define AS1 __attribute__((address_space(1)))
#define AS3 __attribute__((address_space(3)))

__device__ __forceinline__ void gload_lds16(const bf16* gp, bf16* lp) {
  __builtin_amdgcn_global_load_lds((const AS1 void*)gp, (AS3 void*)lp, 16, 0, 0);
}

__device__ __forceinline__ float fast_exp2(float x) {
#if __has_builtin(__builtin_amdgcn_exp2f)
  return __builtin_amdgcn_exp2f(x);
#else
  return exp2f(x);
#endif
}

__device__ __forceinline__ void store_c(bf16* C, size_t idx, float v) { C[idx] = __float2bfloat16(v); }
__device__ __forceinline__ void store_c(float* C, size_t idx, float v) { C[idx] = v; }

struct __align__(8) b16x4 { bf16 a, b, c, d; };

// ---------------------------------------------------------------------------
// prep_all: ONE kernel for (a) fp32->bf16 convert of x, (b) RoPE cos/sin
// table, (c) all 8 weight transposes. Block-ranged dispatch.
// r5 lesson: trig calls live ONLY in the tab range.
// ---------------------------------------------------------------------------
struct PrepArgs {
  const float* src[8];
  bf16* dst[8];
  int R[8], C[8], cum[8];
};

__global__ void prep_all(const float* __restrict__ x, bf16* __restrict__ xbf,
                         float2* __restrict__ ctab, PrepArgs a)
{
  const int blk = blockIdx.x;
  const int tid = threadIdx.x;
  if (blk < 8192) {                       // ---- cvt x -> xbf ----
    const int i = (blk * 256 + tid) * 4;
    const float4 v = *(const float4*)(x + i);
    xbf[i + 0] = __float2bfloat16(v.x);
    xbf[i + 1] = __float2bfloat16(v.y);
    xbf[i + 2] = __float2bfloat16(v.z);
    xbf[i + 3] = __float2bfloat16(v.w);
    return;
  }
  if (blk < 8448) {                       // ---- RoPE table ----
    const int idx = (blk - 8192) * 256 + tid;   // 65536 entries
    const int i = idx & 31;
    const int s = idx >> 5;
    const float inv = fast_exp2(-(float)i * 0.41524101186092029f);
    const float ang = (float)s * inv;
    ctab[idx] = make_float2(cosf(ang), sinf(ang));
    return;
  }
  // ---- weight transposes (fp32 [R][C] -> bf16 [C][R]) ----
  __shared__ bf16 t[32][33];
  const int pb = blk - 8448;
  int e = 0;
  while (e < 7 && pb >= a.cum[e]) ++e;
  const int lt = pb - (e ? a.cum[e - 1] : 0);
  const int R = a.R[e], C = a.C[e];
  const int tpr = C >> 5;
  const int bx = lt % tpr, by = lt / tpr;
  const float* in = a.src[e];
  bf16* out = a.dst[e];
  const int c0 = bx * 32, r0 = by * 32;
  const int tx = tid & 31, ty = tid >> 5;
  for (int i = 0; i < 4; ++i)
    t[ty + 8 * i][tx] = __float2bfloat16(in[(size_t)(r0 + ty + 8 * i) * C + c0 + tx]);
  __syncthreads();
  for (int i = 0; i < 4; ++i)
    out[(size_t)(c0 + ty + 8 * i) * R + r0 + tx] = t[tx][ty + 8 * i];
}

// ---------------------------------------------------------------------------
// Generic bf16 GEMM, C = A @ B with B supplied transposed (Bt[N][K]).
// 128x128 tile, r6 double-buffered staging (counted vmcnt(4), raw
// s_barrier). r10 post-mortem: this is the measured local optimum — BN=64
// (+occupancy, -reuse) lost 10us/gemm; split-K (r9) and waitcnt depth (r7)
// also null/negative. MODE 4: n0<1024 -> latcat; n0>=1024 -> k_rope with
// RoPE fused via ctab. MODE 0: plain f32 store.
// ---------------------------------------------------------------------------
template <typename CT, int MODE>
__global__ void gemm_bt(const bf16* __restrict__ A, int lda,
                        const bf16* __restrict__ Bt,
                        CT* __restrict__ C, bf16* __restrict__ C2, int ldc,
                        int K, const float2* __restrict__ ctab)
{
  __shared__ __align__(16) bf16 As[2][128 * 32];
  __shared__ __align__(16) bf16 Bs[2][128 * 32];
  const int tid  = threadIdx.x;
  const int wave = tid >> 6, lane = tid & 63;
  const int quad = lane >> 4, l16 = lane & 15;
  const int m0 = blockIdx.y * 128, n0 = blockIdx.x * 128;
  const int wm = (wave >> 1) * 64, wn = (wave & 1) * 64;

  f32x4 acc[4][4];
#pragma unroll
  for (int i = 0; i < 4; ++i)
#pragma unroll
    for (int j = 0; j < 4; ++j) acc[i][j] = (f32x4){0.f, 0.f, 0.f, 0.f};

  const int r1  = tid >> 2;
  const int ks1 = (tid & 3) * 8;

  gload_lds16(A  + (size_t)(m0 + r1)      * lda + ks1, &As[0][tid * 8]);
  gload_lds16(A  + (size_t)(m0 + r1 + 64) * lda + ks1, &As[0][(tid + 256) * 8]);
  gload_lds16(Bt + (size_t)(n0 + r1)      * K   + ks1, &Bs[0][tid * 8]);
  gload_lds16(Bt + (size_t)(n0 + r1 + 64) * K   + ks1, &Bs[0][(tid + 256) * 8]);

  int cur = 0;
  for (int k0 = 0; k0 < K; k0 += 32) {
    if (k0 + 32 < K) {                  // prefetch next tile into buf^1
      const int kn = k0 + 32;
      const int nxt = cur ^ 1;
      gload_lds16(A  + (size_t)(m0 + r1)      * lda + kn + ks1, &As[nxt][tid * 8]);
      gload_lds16(A  + (size_t)(m0 + r1 + 64) * lda + kn + ks1, &As[nxt][(tid + 256) * 8]);
      gload_lds16(Bt + (size_t)(n0 + r1)      * K   + kn + ks1, &Bs[nxt][tid * 8]);
      gload_lds16(Bt + (size_t)(n0 + r1 + 64) * K   + kn + ks1, &Bs[nxt][(tid + 256) * 8]);
      asm volatile("s_waitcnt vmcnt(4)" ::: "memory");
    } else {
      asm volatile("s_waitcnt vmcnt(0)" ::: "memory");
    }
    __builtin_amdgcn_s_barrier();

    short8 af[4], bf_[4];
#pragma unroll
    for (int mt = 0; mt < 4; ++mt)
      af[mt] = *(const short8*)&As[cur][(wm + mt * 16 + l16) * 32 + quad * 8];
#pragma unroll
    for (int nt = 0; nt < 4; ++nt)
      bf_[nt] = *(const short8*)&Bs[cur][(wn + nt * 16 + l16) * 32 + quad * 8];
#pragma unroll
    for (int mt = 0; mt < 4; ++mt)
#pragma unroll
      for (int nt = 0; nt < 4; ++nt)
        acc[mt][nt] = __builtin_amdgcn_mfma_f32_16x16x32_bf16(af[mt], bf_[nt], acc[mt][nt], 0, 0, 0);
    __builtin_amdgcn_s_barrier();
    cur ^= 1;
  }

  if (MODE == 0) {
#pragma unroll
    for (int mt = 0; mt < 4; ++mt) {
      const int row = m0 + wm + mt * 16 + quad * 4;
#pragma unroll
      for (int nt = 0; nt < 4; ++nt) {
        const int cn = n0 + wn + nt * 16 + l16;
        const f32x4 v = acc[mt][nt];
#pragma unroll
        for (int r = 0; r < 4; ++r)
          store_c(C, (size_t)(row + r) * ldc + cn, v[r]);
      }
    }
  } else if (MODE == 4) {
    if (n0 < 1024) {
      // latcat path (whole block has cn < 1024)
#pragma unroll
      for (int mt = 0; mt < 4; ++mt) {
        const int row = m0 + wm + mt * 16 + quad * 4;
#pragma unroll
        for (int nt = 0; nt < 4; ++nt) {
          const int cn = n0 + wn + nt * 16 + l16;
          const f32x4 v = acc[mt][nt];
#pragma unroll
          for (int r = 0; r < 4; ++r)
            store_c(C, (size_t)(row + r) * 1024 + cn, v[r]);
        }
      }
    } else {
      // k_rope path: RoPE via table lookup (no trig calls -> no spills)
#pragma unroll
      for (int mt = 0; mt < 4; ++mt) {
        const int row = m0 + wm + mt * 16 + quad * 4;
        f32x4 w[4];
#pragma unroll
        for (int nt = 0; nt < 4; ++nt) w[nt] = acc[mt][nt];
#pragma unroll
        for (int r = 0; r < 4; ++r) {
          const int s = (row + r) & 2047;
          const float2 cs0 = ctab[(s << 5) + l16];
          const float2 cs1 = ctab[(s << 5) + 16 + l16];
          const float x1a = w[0][r], x2a = w[2][r];
          const float x1b = w[1][r], x2b = w[3][r];
          w[0][r] = x1a * cs0.x - x2a * cs0.y;
          w[2][r] = x2a * cs0.x + x1a * cs0.y;
          w[1][r] = x1b * cs1.x - x2b * cs1.y;
          w[3][r] = x2b * cs1.x + x1b * cs1.y;
        }
#pragma unroll
        for (int nt = 0; nt < 4; ++nt) {
          const int cn2 = n0 + wn + nt * 16 + l16 - 1024;
          const int g = ((cn2 >> 6) << 7) + 64 + (cn2 & 63);
#pragma unroll
          for (int r = 0; r < 4; ++r)
            C2[(size_t)(row + r) * 2048 + g] = __float2bfloat16(w[nt][r]);
        }
      }
    }
  }
}

// ---------------------------------------------------------------------------
// Fused up-projection GEMM: k_nope+vT (N=3072) and q-interleave (N=2048).
// K=512, lda=1024. grid=(40,32) = 1280 blocks = 5/CU. r6 dbuf staging.
// ---------------------------------------------------------------------------
__global__ void gemm_up_fused(const bf16* __restrict__ latcat,
                              const bf16* __restrict__ wtUP,
                              const bf16* __restrict__ wtQcat,
                              bf16* __restrict__ vT, bf16* __restrict__ kfull,
                              bf16* __restrict__ qfull,
                              const float2* __restrict__ ctab)
{
  const bool is2 = (blockIdx.x >= 24);
  const bf16* A  = latcat + (is2 ? 512 : 0);
  const bf16* Bt = is2 ? wtQcat : wtUP;
  const int n0 = (is2 ? (int)blockIdx.x - 24 : (int)blockIdx.x) * 128;
  const int K = 512, lda = 1024;

  __shared__ __align__(16) bf16 As[2][128 * 32];
  __shared__ __align__(16) bf16 Bs[2][128 * 32];
  const int tid  = threadIdx.x;
  const int wave = tid >> 6, lane = tid & 63;
  const int quad = lane >> 4, l16 = lane & 15;
  const int m0 = blockIdx.y * 128;
  const int wm = (wave >> 1) * 64, wn = (wave & 1) * 64;

  f32x4 acc[4][4];
#pragma unroll
  for (int i = 0; i < 4; ++i)
#pragma unroll
    for (int j = 0; j < 4; ++j) acc[i][j] = (f32x4){0.f, 0.f, 0.f, 0.f};

  const int r1  = tid >> 2;
  const int ks1 = (tid & 3) * 8;

  gload_lds16(A  + (size_t)(m0 + r1)      * lda + ks1, &As[0][tid * 8]);
  gload_lds16(A  + (size_t)(m0 + r1 + 64) * lda + ks1, &As[0][(tid + 256) * 8]);
  gload_lds16(Bt + (size_t)(n0 + r1)      * K   + ks1, &Bs[0][tid * 8]);
  gload_lds16(Bt + (size_t)(n0 + r1 + 64) * K   + ks1, &Bs[0][(tid + 256) * 8]);

  int cur = 0;
  for (int k0 = 0; k0 < K; k0 += 32) {
    if (k0 + 32 < K) {
      const int kn = k0 + 32;
      const int nxt = cur ^ 1;
      gload_lds16(A  + (size_t)(m0 + r1)      * lda + kn + ks1, &As[nxt][tid * 8]);
      gload_lds16(A  + (size_t)(m0 + r1 + 64) * lda + kn + ks1, &As[nxt][(tid + 256) * 8]);
      gload_lds16(Bt + (size_t)(n0 + r1)      * K   + kn + ks1, &Bs[nxt][tid * 8]);
      gload_lds16(Bt + (size_t)(n0 + r1 + 64) * K   + kn + ks1, &Bs[nxt][(tid + 256) * 8]);
      asm volatile("s_waitcnt vmcnt(4)" ::: "memory");
    } else {
      asm volatile("s_waitcnt vmcnt(0)" ::: "memory");
    }
    __builtin_amdgcn_s_barrier();

    short8 af[4], bf_[4];
#pragma unroll
    for (int mt = 0; mt < 4; ++mt)
      af[mt] = *(const short8*)&As[cur][(wm + mt * 16 + l16) * 32 + quad * 8];
#pragma unroll
    for (int nt = 0; nt < 4; ++nt)
      bf_[nt] = *(const short8*)&Bs[cur][(wn + nt * 16 + l16) * 32 + quad * 8];
#pragma unroll
    for (int mt = 0; mt < 4; ++mt)
#pragma unroll
      for (int nt = 0; nt < 4; ++nt)
        acc[mt][nt] = __builtin_amdgcn_mfma_f32_16x16x32_bf16(af[mt], bf_[nt], acc[mt][nt], 0, 0, 0);
    __builtin_amdgcn_s_barrier();
    cur ^= 1;
  }

  if (is2) {
    if (n0 < 1024) {
#pragma unroll
      for (int mt = 0; mt < 4; ++mt) {
        const int row = m0 + wm + mt * 16 + quad * 4;
#pragma unroll
        for (int nt = 0; nt < 4; ++nt) {
          const int cn = n0 + wn + nt * 16 + l16;
          const int g = (((cn >> 6) & 15) << 7) + ((cn >> 10) << 6) + (cn & 63);
          const f32x4 v = acc[mt][nt];
#pragma unroll
          for (int r = 0; r < 4; ++r)
            qfull[(size_t)(row + r) * 2048 + g] = __float2bfloat16(v[r]);
        }
      }
    } else {
      // q_rope half: RoPE via table lookup, then interleave store
#pragma unroll
      for (int mt = 0; mt < 4; ++mt) {
        const int row = m0 + wm + mt * 16 + quad * 4;
        f32x4 w[4];
#pragma unroll
        for (int nt = 0; nt < 4; ++nt) w[nt] = acc[mt][nt];
#pragma unroll
        for (int r = 0; r < 4; ++r) {
          const int s = (row + r) & 2047;
          const float2 cs0 = ctab[(s << 5) + l16];
          const float2 cs1 = ctab[(s << 5) + 16 + l16];
          const float x1a = w[0][r], x2a = w[2][r];
          const float x1b = w[1][r], x2b = w[3][r];
          w[0][r] = x1a * cs0.x - x2a * cs0.y;
          w[2][r] = x2a * cs0.x + x1a * cs0.y;
          w[1][r] = x1b * cs1.x - x2b * cs1.y;
          w[3][r] = x2b * cs1.x + x1b * cs1.y;
        }
#pragma unroll
        for (int nt = 0; nt < 4; ++nt) {
          const int cn = n0 + wn + nt * 16 + l16;
          const int g = (((cn >> 6) & 15) << 7) + ((cn >> 10) << 6) + (cn & 63);
#pragma unroll
          for (int r = 0; r < 4; ++r)
            qfull[(size_t)(row + r) * 2048 + g] = __float2bfloat16(w[nt][r]);
        }
      }
    }
  } else {
#pragma unroll
    for (int mt = 0; mt < 4; ++mt) {
      const int row = m0 + wm + mt * 16 + quad * 4;
#pragma unroll
      for (int nt = 0; nt < 4; ++nt) {
        const int cn = n0 + wn + nt * 16 + l16;
        const f32x4 v = acc[mt][nt];
        if (cn < 1024) {
          const int g = ((cn >> 6) << 7) + (cn & 63);
#pragma unroll
          for (int r = 0; r < 4; ++r)
            kfull[(size_t)(row + r) * 2048 + g] = __float2bfloat16(v[r]);
        } else {
          const int cn2 = cn - 1024;
          const int bb = row >> 11, s0 = row & 2047;
          b16x4 pk;
          pk.a = __float2bfloat16(v[0]); pk.b = __float2bfloat16(v[1]);
          pk.c = __float2bfloat16(v[2]); pk.d = __float2bfloat16(v[3]);
          *(b16x4*)(vT + ((size_t)(bb * 2048 + cn2)) * 2048 + s0) = pk;
        }
      }
    }
  }
}

// ---------------------------------------------------------------------------
// Flash attention v10 (causal, equal-work key-split, SYNC-FREE). Block
// (bh,j): phase A = upper key-half of qt=15-j -> unnorm partial to poA + lA;
// phase B = lower half of qt=j -> unnorm into Y + lB. Every block = 17
// steps; combine in a separate merge kernel (kernel-boundary visibility).
// r8 measured: 57.3 us, occupancy flat 18%, MfmaUtil 25.7.
// ---------------------------------------------------------------------------
__device__ __forceinline__ void attn_phase(
    const bf16* __restrict__ Q, const bf16* __restrict__ Kf,
    const bf16* __restrict__ VT,
    size_t kqbase, size_t vtbase, int qt, int t0, int t1,
    bf16* __restrict__ Ks, bf16* __restrict__ VTs, bf16* __restrict__ Psw,
    f32x4 (&o)[2][8], f32x4 (&lacc)[2], const short8 ones,
    int wave, int quad, int l16, int krow, int kcol, int vrow, int vcol)
{
  const float C2 = 0.08838834764831845f * 1.4426950408889634f; // scale*log2e
  const float MNEG = -30.0f;
  const int wq0 = qt * 128 + wave * 32;        // this wave's first q row

  short8 qf[2][4];
#pragma unroll
  for (int m = 0; m < 2; ++m) {
    const bf16* qp = Q + kqbase + (size_t)(wq0 + m * 16 + l16) * 2048 + quad * 8;
#pragma unroll
    for (int kc = 0; kc < 4; ++kc) qf[m][kc] = *(const short8*)(qp + kc * 32);
  }

  short8 kg[4], vg[4];
  {
    const int kk = t0 * 64;
#pragma unroll
    for (int i = 0; i < 4; ++i)
      kg[i] = *(const short8*)(Kf + kqbase + (size_t)(kk + krow + i * 16) * 2048 + kcol);
#pragma unroll
    for (int i = 0; i < 4; ++i)
      vg[i] = *(const short8*)(VT + vtbase + (size_t)(vrow + i * 32) * 2048 + kk + vcol);
  }

  for (int t = t0; t < t1; ++t) {
    const int k0 = t * 64;
    __syncthreads();                    // all waves done reading prev tile
#pragma unroll
    for (int i = 0; i < 4; ++i) {
      const int rw = krow + i * 16;
      *(short8*)&Ks[rw * 128 + (kcol ^ ((rw & 7) * 8))] = kg[i];
    }
#pragma unroll
    for (int i = 0; i < 4; ++i) {
      const int rw = vrow + i * 32;
      *(short8*)&VTs[rw * 64 + (vcol ^ ((rw & 7) * 8))] = vg[i];
    }
    __syncthreads();                    // tile t visible
    if (t + 1 < t1) {                   // prefetch t+1 under compute
      const int kn = k0 + 64;
#pragma unroll
      for (int i = 0; i < 4; ++i)
        kg[i] = *(const short8*)(Kf + kqbase + (size_t)(kn + krow + i * 16) * 2048 + kcol);
#pragma unroll
      for (int i = 0; i < 4; ++i)
        vg[i] = *(const short8*)(VT + vtbase + (size_t)(vrow + i * 32) * 2048 + kn + vcol);
    }
    if (k0 > wq0 + 31) continue;        // wave fully masked (barriers done)

    // ---- S = Q K^T; both m-strips share each K fragment ----
    f32x4 sf[2][4];
#pragma unroll
    for (int kt = 0; kt < 4; ++kt) {
      sf[0][kt] = (f32x4){0, 0, 0, 0};
      sf[1][kt] = (f32x4){0, 0, 0, 0};
    }
#pragma unroll
    for (int kt = 0; kt < 4; ++kt) {
#pragma unroll
      for (int kc = 0; kc < 4; ++kc) {
        const short8 bfr = *(const short8*)&Ks[(kt * 16 + l16) * 128 +
                                              ((kc * 32 + quad * 8) ^ ((l16 & 7) * 8))];
        sf[0][kt] = __builtin_amdgcn_mfma_f32_16x16x32_bf16(qf[0][kc], bfr, sf[0][kt], 0, 0, 0);
        sf[1][kt] = __builtin_amdgcn_mfma_f32_16x16x32_bf16(qf[1][kc], bfr, sf[1][kt], 0, 0, 0);
      }
    }
    // ---- causal mask (diagonal tiles only) ----
#pragma unroll
    for (int m = 0; m < 2; ++m) {
      const int row0m = wq0 + m * 16 + quad * 4;
      if (k0 + 63 > row0m) {
#pragma unroll
        for (int kt = 0; kt < 4; ++kt) {
          const int col = k0 + kt * 16 + l16;
#pragma unroll
          for (int r = 0; r < 4; ++r)
            sf[m][kt][r] = (col > row0m + r) ? -3e38f : sf[m][kt][r];
        }
      }
    }
    // ---- p = exp2(s*C2 - M) -> Ps (quad-XOR swizzle: conflict-free) ----
#pragma unroll
    for (int m = 0; m < 2; ++m)
#pragma unroll
      for (int kt = 0; kt < 4; ++kt)
#pragma unroll
        for (int r = 0; r < 4; ++r) {
          const float p = fast_exp2(__builtin_fmaf(sf[m][kt][r], C2, MNEG));
          const int prow = m * 16 + quad * 4 + r;
          const int pcol = (kt * 16 + l16) ^ (quad * 16);
          Psw[prow * 64 + pcol] = __float2bfloat16(p);
        }
    asm volatile("s_waitcnt lgkmcnt(0)" ::: "memory");
    // ---- O += P V, l += P*1; V fragments shared by both strips ----
#pragma unroll
    for (int kc = 0; kc < 2; ++kc) {
      short8 ap[2];
      const int acol = (kc * 32 + quad * 8) ^ (((l16 >> 2) & 3) * 16);
      ap[0] = *(const short8*)&Psw[l16 * 64 + acol];
      lacc[0] = __builtin_amdgcn_mfma_f32_16x16x32_bf16(ap[0], ones, lacc[0], 0, 0, 0);
      ap[1] = *(const short8*)&Psw[(16 + l16) * 64 + acol];
      lacc[1] = __builtin_amdgcn_mfma_f32_16x16x32_bf16(ap[1], ones, lacc[1], 0, 0, 0);
#pragma unroll
      for (int dt = 0; dt < 8; ++dt) {
        const short8 vb = *(const short8*)&VTs[(dt * 16 + l16) * 64 +
                                              ((kc * 32 + quad * 8) ^ ((l16 & 7) * 8))];
        o[0][dt] = __builtin_amdgcn_mfma_f32_16x16x32_bf16(ap[0], vb, o[0][dt], 0, 0, 0);
        o[1][dt] = __builtin_amdgcn_mfma_f32_16x16x32_bf16(ap[1], vb, o[1][dt], 0, 0, 0);
      }
    }
  }
}

__global__ __launch_bounds__(256, 2) void attn10_kernel(
    const bf16* __restrict__ Q, const bf16* __restrict__ Kf,
    const bf16* __restrict__ VT, bf16* __restrict__ Y,
    bf16* __restrict__ poA, float* __restrict__ lA, float* __restrict__ lB)
{
  __shared__ __align__(16) bf16 Ks[64 * 128];    // [key][d], XOR-swizzled
  __shared__ __align__(16) bf16 VTs[128 * 64];   // [d][key], XOR-swizzled
  __shared__ __align__(16) bf16 Ps[4 * 32 * 64]; // per-wave P, quad-XOR-swizzled
  const int tid  = threadIdx.x;
  const int wave = tid >> 6, lane = tid & 63;
  const int quad = lane >> 4, l16 = lane & 15;
  const int bh = blockIdx.x;                     // fastest-varying -> L2 locality
  const int j  = blockIdx.y;
  const int qt_A = 15 - j;                       // phase A: upper key-half
  const int qt_B = j;                            // phase B: lower key-half
  const size_t kqbase = ((size_t)(bh >> 4) * 2048) * 2048 + (bh & 15) * 128;
  const size_t vtbase = (size_t)bh * 128 * 2048;

  short8 ones;
#pragma unroll
  for (int i = 0; i < 8; ++i) ones[i] = (short)0x3F80;   // bf16 1.0

  const int krow = tid >> 4, kcol = (tid & 15) * 8;  // K: 4 instr x 16 rows
  const int vrow = tid >> 3, vcol = (tid & 7) * 8;   // VT: 4 instr x 32 rows
  bf16* Psw = Ps + wave * (32 * 64);

  f32x4 o[2][8];
  f32x4 lacc[2];

  // ---------------- PHASE A: keys [qt_A+1, 2qt_A+2) of q-tile qt_A -------
#pragma unroll
  for (int m = 0; m < 2; ++m)
#pragma unroll
    for (int i = 0; i < 8; ++i) o[m][i] = (f32x4){0, 0, 0, 0};
  lacc[0] = (f32x4){0, 0, 0, 0};
  lacc[1] = (f32x4){0, 0, 0, 0};
  attn_phase(Q, Kf, VT, kqbase, vtbase, qt_A, qt_A + 1, 2 * qt_A + 2,
             Ks, VTs, Psw, o, lacc, ones, wave, quad, l16, krow, kcol, vrow, vcol);
  {
    bf16* po = poA + ((size_t)(bh * 16 + qt_A) << 14);
    float* pl = lA + ((bh * 16 + qt_A) << 7);
#pragma unroll
    for (int m = 0; m < 2; ++m)
#pragma unroll
      for (int r = 0; r < 4; ++r) {
        const int rl = wave * 32 + m * 16 + quad * 4 + r;
#pragma unroll
        for (int dt = 0; dt < 8; ++dt)
          po[rl * 128 + dt * 16 + l16] = __float2bfloat16(o[m][dt][r]);
        if (l16 == 0) pl[rl] = lacc[m][r];
      }
  }

  // ---------------- PHASE B: keys [0, qt_B+1) of q-tile qt_B -------------
#pragma unroll
  for (int m = 0; m < 2; ++m)
#pragma unroll
    for (int i = 0; i < 8; ++i) o[m][i] = (f32x4){0, 0, 0, 0};
  lacc[0] = (f32x4){0, 0, 0, 0};
  lacc[1] = (f32x4){0, 0, 0, 0};
  attn_phase(Q, Kf, VT, kqbase, vtbase, qt_B, 0, qt_B + 1,
             Ks, VTs, Psw, o, lacc, ones, wave, quad, l16, krow, kcol, vrow, vcol);
  {
    float* pl = lB + ((bh * 16 + qt_B) << 7);
#pragma unroll
    for (int m = 0; m < 2; ++m)
#pragma unroll
      for (int r = 0; r < 4; ++r) {
        const int rl = wave * 32 + m * 16 + quad * 4 + r;
#pragma unroll
        for (int dt = 0; dt < 8; ++dt)
          Y[kqbase + (size_t)(qt_B * 128 + rl) * 2048 + dt * 16 + l16] =
              __float2bfloat16(o[m][dt][r]);
        if (l16 == 0) pl[rl] = lacc[m][r];
      }
  }
}

// ---------------------------------------------------------------------------
// Merge: Y = (Y + poA) / (lA + lB), elementwise in place. 8 bf16/thread.
// ---------------------------------------------------------------------------
__global__ void attn_merge(bf16* __restrict__ Y, const bf16* __restrict__ poA,
                           const float* __restrict__ lA, const float* __restrict__ lB)
{
  const int t = blockIdx.x * 256 + threadIdx.x;
  const size_t e = (size_t)t * 8;                // 8.39M elems / 8
  const int col = (int)(e & 2047);
  const int row = (int)(e >> 11);                // b*2048 + s
  const int b = row >> 11, s = row & 2047;
  const int h = col >> 7, dcol = col & 127;
  const int bh = b * 16 + h, qt = s >> 7, rl = s & 127;
  const int li = ((bh * 16 + qt) << 7) + rl;
  const float inv = 1.0f / (lA[li] + lB[li]);
  const short8 va = *(const short8*)(poA + (((size_t)(bh * 16 + qt)) << 14) + rl * 128 + dcol);
  const short8 vb = *(const short8*)(Y + e);
  short8 out;
#pragma unroll
  for (int i = 0; i < 8; ++i) {
    const float fa = __bfloat162float(((const bf16*)&va)[i]);
    const float fb = __bfloat162float(((const bf16*)&vb)[i]);
    ((bf16*)&out)[i] = __float2bfloat16((fa + fb) * inv);
  }
  *(short8*)(Y + e) = out;
}

// ---------------------------------------------------------------------------
extern "C" void kernel_launch(void* const* d_in, const int* in_sizes, int n_in,
                              void* d_out, int out_size, void* d_ws, size_t ws_size,
                              hipStream_t stream)
{
  const float* x      = (const float*)d_in[0];
  const float* Wkvd   = (const float*)d_in[1];
  const float* Wqd    = (const float*)d_in[2];
  const float* Wku    = (const float*)d_in[3];
  const float* Wqu    = (const float*)d_in[4];
  const float* Wvu    = (const float*)d_in[5];
  const float* Wropek = (const float*)d_in[6];
  const float* Wropeq = (const float*)d_in[7];
  const float* Wo     = (const float*)d_in[8];

  char* ws = (char*)d_ws;
  size_t off = 0;
  auto alloc = [&](size_t elems) {
    bf16* p = (bf16*)(ws + off);
    off += ((elems * sizeof(bf16) + 255) & ~(size_t)255);
    return p;
  };
  // Region A — dead before attn; ybuf (16 MB) aliases it.
  bf16* wtX    = alloc((size_t)2048 * 2048); // Wkvd^T | Wqd^T | Wropek^T
  bf16* wtUP   = alloc((size_t)3072 * 512);  // Wku^T | Wvu^T
  bf16* wtQcat = alloc((size_t)2048 * 512);  // Wqu^T | Wropeq^T
  bf16* latcat = alloc((size_t)4096 * 1024);
  // end region A (21 MB)
  bf16* wt_o   = alloc((size_t)2048 * 2048);
  bf16* xbf    = alloc((size_t)4096 * 2048);
  bf16* qfull  = alloc((size_t)4096 * 2048);
  bf16* kfull  = alloc((size_t)4096 * 2048);
  float2* ctab = (float2*)alloc((size_t)65536 * 4);  // 512 KB cos/sin table
  bf16* ybuf   = (bf16*)ws;
  bf16* vT     = (bf16*)d_out;
  // attn10 partials in dead-at-attn regions: poA = xbf (dead after gemm1);
  // lA/lB in latcat tail [16MB, 16.5MB), outside ybuf's [0,16MB) alias.
  bf16*  poA = xbf;
  float* lA  = (float*)(ws + 16777216);
  float* lB  = (float*)(ws + 16777216 + 262144);
  (void)ws_size; (void)in_sizes; (void)n_in; (void)out_size;

  PrepArgs pa;
  const float* srcs[8] = {Wkvd, Wqd, Wropek, Wku, Wvu, Wqu, Wropeq, Wo};
  bf16* dsts[8] = {wtX, wtX + (size_t)512 * 2048, wtX + (size_t)1024 * 2048,
                   wtUP, wtUP + (size_t)1024 * 512,
                   wtQcat, wtQcat + (size_t)1024 * 512, wt_o};
  const int Rs[8] = {2048, 2048, 2048, 512, 512, 512, 512, 2048};
  const int Cs[8] = {512, 512, 1024, 1024, 2048, 1024, 1024, 2048};
  int cum = 0;
  for (int e = 0; e < 8; ++e) {
    pa.src[e] = srcs[e]; pa.dst[e] = dsts[e]; pa.R[e] = Rs[e]; pa.C[e] = Cs[e];
    cum += (Rs[e] >> 5) * (Cs[e] >> 5);
    pa.cum[e] = cum;
  }
  // cvt + rope-table + all transposes in ONE launch
  prep_all<<<8448 + cum, 256, 0, stream>>>(x, xbf, ctab, pa);

  // latcat = x @ [W_kv_d | W_q_d]  AND  k_rope = x @ W_rope_k (RoPE fused)
  gemm_bt<bf16, 4><<<dim3(16, 32), 256, 0, stream>>>(xbf, 2048, wtX, latcat, kfull, 1024, 2048, ctab);
  // k_nope+vT AND q-interleave (q_rope RoPE fused), single launch
  gemm_up_fused<<<dim3(40, 32), 256, 0, stream>>>(latcat, wtUP, wtQcat, vT, kfull, qfull, ctab);

  attn10_kernel<<<dim3(32, 16), 256, 0, stream>>>(qfull, kfull, vT, ybuf, poA, lA, lB);
  attn_merge<<<4096, 256, 0, stream>>>(ybuf, poA, lA, lB);

  // out = y @ W_o (plain f32 store)
  gemm_bt<float, 0><<<dim3(16, 32), 256, 0, stream>>>(ybuf, 2048, wt_o, (float*)d_out, (bf16*)nullptr, 2048, 2048, ctab);
}